// Round 8
// baseline (1670.056 us; speedup 1.0000x reference)
//
#include <hip/hip_runtime.h>

typedef unsigned short u16;
typedef unsigned int u32;
typedef __attribute__((ext_vector_type(8))) short short8;
typedef __attribute__((ext_vector_type(4))) float f4;

#define DEV static __device__ __forceinline__

constexpr int BB = 16, NN = 2048, DD = 1024, HH = 8, DHD = 64, II = 512, LL = 64, DEPTHC = 6, FFC = 4096;

DEV u16 f2bf(float f) {
  union { float f; u32 u; } v; v.f = f;
  u32 r = v.u + 0x7FFFu + ((v.u >> 16) & 1u);
  return (u16)(r >> 16);
}

DEV u32 pack2(float lo, float hi) {
  return (u32)f2bf(lo) | ((u32)f2bf(hi) << 16);
}

typedef const u32 __attribute__((address_space(1)))* gas_p;
typedef u32 __attribute__((address_space(3)))* las_p;
DEV void gl_lds16(const void* g, void* l) {
  __builtin_amdgcn_global_load_lds((gas_p)g, (las_p)l, 16, 0, 0);
}

// ---------------- mask prefix-scan: per batch, list of unmasked (mask==0) indices ----------------
__global__ __launch_bounds__(256) void maskscan_k(const int* __restrict__ mask,
    int* __restrict__ idx, int* __restrict__ cnt) {
  int b = blockIdx.x, tid = threadIdx.x;
  int lane = tid & 63, wv = tid >> 6;
  const int* mrow = mask + (size_t)b * NN;
  int base = tid * 8;
  int keep[8]; int local = 0;
  #pragma unroll
  for (int j = 0; j < 8; j++) { keep[j] = (mrow[base + j] == 0); local += keep[j]; }
  int incl = local;
  #pragma unroll
  for (int off = 1; off < 64; off <<= 1) {
    int v = __shfl_up(incl, off, 64);
    if (lane >= off) incl += v;
  }
  __shared__ int wsum[4];
  if (lane == 63) wsum[wv] = incl;
  __syncthreads();
  int wbase = 0;
  for (int w = 0; w < wv; w++) wbase += wsum[w];
  int pos = wbase + incl - local;
  #pragma unroll
  for (int j = 0; j < 8; j++) if (keep[j]) idx[(size_t)b * NN + pos++] = base + j;
  if (tid == 255) cnt[b] = wbase + incl;
}

// ---------------- zero small buffer ----------------
__global__ void zero_k(float* __restrict__ p, int n) {
  int i = blockIdx.x * 256 + threadIdx.x;
  if (i < n) p[i] = 0.f;
}

// ---------------- W1 / W2 transpose: 64x64 tiles, 1024 tiles per depth ----------------
// W1: R=1024 C=4096 ctLog=6 ; W2: R=4096 C=1024 ctLog=4
__global__ __launch_bounds__(256) void transp_w_k(const float* __restrict__ Wa, u16* __restrict__ WTa,
    int R, int C, int ctLog) {
  __shared__ float t[64][65];
  int gid = blockIdx.x;
  int depth = gid >> 10;
  int l = gid & 1023;
  int c0 = (l & ((1 << ctLog) - 1)) << 6;
  int r0 = (l >> ctLog) << 6;
  const float* in = Wa + (size_t)depth * 4096 * 1024;
  u16* o1 = WTa + (size_t)depth * 4096 * 1024;
  int tid = threadIdx.x;
  int lr = tid >> 4, lc4 = (tid & 15) * 4;
  #pragma unroll
  for (int p = 0; p < 4; p++) {
    int row = p * 16 + lr;
    float4 v = *(const float4*)&in[(size_t)(r0 + row) * C + c0 + lc4];
    t[row][lc4] = v.x; t[row][lc4+1] = v.y; t[row][lc4+2] = v.z; t[row][lc4+3] = v.w;
  }
  __syncthreads();
  int oc = tid >> 3;      // 0..31 output row within tile, per pass
  int rg = tid & 7;       // 8-thread group along output row
  #pragma unroll
  for (int p = 0; p < 2; p++) {
    int c = p * 32 + oc;
    float v[8];
    #pragma unroll
    for (int k = 0; k < 8; k++) v[k] = t[rg * 8 + k][c];
    int4 o;
    o.x = (int)pack2(v[0], v[1]); o.y = (int)pack2(v[2], v[3]);
    o.z = (int)pack2(v[4], v[5]); o.w = (int)pack2(v[6], v[7]);
    *(int4*)&o1[(size_t)(c0 + c) * R + r0 + rg * 8] = o;
  }
}

// ---------------- fused pre-pass: Wq/Wkv/Wo transposes (+kv fold) | LN-gather | lat-init ----------
// ranges: [0,3072) weights (512/depth) ; [3072,35840) ln_gather ; [35840,36864) lat_init
__global__ __launch_bounds__(256) void qkvo_fused_k(
    const float* __restrict__ WqA, const float* __restrict__ WkvA, const float* __restrict__ WoA,
    const float* __restrict__ lnwA, const float* __restrict__ lnbA,
    u16* __restrict__ WqkvTA, u16* __restrict__ WoTA, u16* __restrict__ WkvTfA,
    float* __restrict__ biaskvA,
    const float* __restrict__ x, const int* __restrict__ idx, const int* __restrict__ cnt,
    u16* __restrict__ xcomp, const float* __restrict__ latents, float* __restrict__ lat) {
  __shared__ float t[64][65];
  __shared__ float red8[8];
  int gid = blockIdx.x;
  int tid = threadIdx.x;
  if (gid < 3072) {
    int depth = gid >> 9;
    int id = gid & 511;
    const float* in; u16* o1; int R, C, c0, r0;
    bool iskv = false;
    if (id < 128)      { in = WqA  + (size_t)depth*1024*512;  R = 1024; C = 512;  int l = id;       c0 = (l & 7) * 64;  r0 = (l >> 3) * 64; o1 = WqkvTA + (size_t)depth*1536*1024; }
    else if (id < 384) { in = WkvA + (size_t)depth*1024*1024; R = 1024; C = 1024; int l = id - 128; c0 = (l & 15) * 64; r0 = (l >> 4) * 64; o1 = WqkvTA + (size_t)depth*1536*1024 + 512*1024; iskv = true; }
    else               { in = WoA  + (size_t)depth*512*1024;  R = 512;  C = 1024; int l = id - 384; c0 = (l & 15) * 64; r0 = (l >> 4) * 64; o1 = WoTA + (size_t)depth*1024*512; }
    int lr = tid >> 4, lc4 = (tid & 15) * 4;
    #pragma unroll
    for (int p = 0; p < 4; p++) {
      int row = p * 16 + lr;
      float4 v = *(const float4*)&in[(size_t)(r0 + row) * C + c0 + lc4];
      t[row][lc4] = v.x; t[row][lc4+1] = v.y; t[row][lc4+2] = v.z; t[row][lc4+3] = v.w;
    }
    int oc = tid >> 3;
    int rg = tid & 7;
    float lw[8], lb[8];
    if (iskv) {
      const float* lnw = lnwA + depth * 1024;
      const float* lnb = lnbA + depth * 1024;
      int rbase = r0 + rg * 8;
      float4 w0 = *(const float4*)&lnw[rbase];
      float4 w1 = *(const float4*)&lnw[rbase + 4];
      float4 b0 = *(const float4*)&lnb[rbase];
      float4 b1 = *(const float4*)&lnb[rbase + 4];
      lw[0]=w0.x; lw[1]=w0.y; lw[2]=w0.z; lw[3]=w0.w; lw[4]=w1.x; lw[5]=w1.y; lw[6]=w1.z; lw[7]=w1.w;
      lb[0]=b0.x; lb[1]=b0.y; lb[2]=b0.z; lb[3]=b0.w; lb[4]=b1.x; lb[5]=b1.y; lb[6]=b1.z; lb[7]=b1.w;
    }
    __syncthreads();
    #pragma unroll
    for (int p = 0; p < 2; p++) {
      int c = p * 32 + oc;
      float v[8];
      #pragma unroll
      for (int k = 0; k < 8; k++) v[k] = t[rg * 8 + k][c];
      int4 o;
      o.x = (int)pack2(v[0], v[1]); o.y = (int)pack2(v[2], v[3]);
      o.z = (int)pack2(v[4], v[5]); o.w = (int)pack2(v[6], v[7]);
      *(int4*)&o1[(size_t)(c0 + c) * R + r0 + rg * 8] = o;
      if (iskv) {
        u16* WkvTf = WkvTfA + (size_t)depth*1024*1024;
        int4 of;
        of.x = (int)pack2(v[0]*lw[0], v[1]*lw[1]); of.y = (int)pack2(v[2]*lw[2], v[3]*lw[3]);
        of.z = (int)pack2(v[4]*lw[4], v[5]*lw[5]); of.w = (int)pack2(v[6]*lw[6], v[7]*lw[7]);
        *(int4*)&WkvTf[(size_t)(c0 + c) * 1024 + r0 + rg * 8] = of;
        float partial = 0.f;
        #pragma unroll
        for (int k = 0; k < 8; k++) partial += lb[k] * v[k];
        partial += __shfl_xor(partial, 1, 64);
        partial += __shfl_xor(partial, 2, 64);
        partial += __shfl_xor(partial, 4, 64);
        if (rg == 0) atomicAdd(&biaskvA[depth*1024 + c0 + c], partial);
      }
    }
    return;
  }
  gid -= 3072;
  if (gid < 32768) {
    // ---- ln_gather (zero-pad to 256-row alignment for 256-row GEMM tiles) ----
    int b = gid >> 11, j = gid & 2047;
    int c = cnt[b];
    if (j >= ((c + 255) & ~255)) return;
    ushort4* orow = (ushort4*)(xcomp + ((size_t)b * NN + j) * DD);
    if (j >= c) { orow[tid] = make_ushort4(0, 0, 0, 0); return; }
    int src = idx[(size_t)b * NN + j];
    const float4* rp = (const float4*)(x + ((size_t)b * NN + src) * DD);
    float4 v = rp[tid];
    float s = v.x + v.y + v.z + v.w;
    float s2 = v.x*v.x + v.y*v.y + v.z*v.z + v.w*v.w;
    #pragma unroll
    for (int off = 32; off >= 1; off >>= 1) {
      s  += __shfl_xor(s, off, 64);
      s2 += __shfl_xor(s2, off, 64);
    }
    int wv = tid >> 6;
    if ((tid & 63) == 0) { red8[wv] = s; red8[4 + wv] = s2; }
    __syncthreads();
    s  = red8[0] + red8[1] + red8[2] + red8[3];
    s2 = red8[4] + red8[5] + red8[6] + red8[7];
    float mu = s * (1.f / DD);
    float var = s2 * (1.f / DD) - mu * mu;
    float rstd = rsqrtf(var + 1e-5f);
    orow[tid] = make_ushort4(f2bf((v.x - mu) * rstd), f2bf((v.y - mu) * rstd),
                             f2bf((v.z - mu) * rstd), f2bf((v.w - mu) * rstd));
    return;
  }
  gid -= 32768;
  // ---- lat_init ----
  int i2 = gid * 256 + tid;
  ((float4*)lat)[i2] = ((const float4*)latents)[i2 & (LL * DD / 4 - 1)];
}

// ---------------- LayerNorm over rows of 1024 (latent path) ----------------
template<bool OUTF32>
__global__ __launch_bounds__(256) void ln_rows_k(const float* __restrict__ in,
    const float* __restrict__ w, const float* __restrict__ bias, void* __restrict__ out) {
  int row = blockIdx.x;
  int tid = threadIdx.x;
  const float4* rp = (const float4*)(in + (size_t)row * DD);
  float4 x = rp[tid];
  float s = x.x + x.y + x.z + x.w;
  float s2 = x.x*x.x + x.y*x.y + x.z*x.z + x.w*x.w;
  #pragma unroll
  for (int off = 32; off >= 1; off >>= 1) {
    s  += __shfl_xor(s, off, 64);
    s2 += __shfl_xor(s2, off, 64);
  }
  __shared__ float red[8];
  int wv = tid >> 6;
  if ((tid & 63) == 0) { red[wv] = s; red[4 + wv] = s2; }
  __syncthreads();
  s  = red[0] + red[1] + red[2] + red[3];
  s2 = red[4] + red[5] + red[6] + red[7];
  float mu = s * (1.f / DD);
  float var = s2 * (1.f / DD) - mu * mu;
  float rstd = rsqrtf(var + 1e-5f);
  float y[4] = {x.x, x.y, x.z, x.w};
  int col = tid * 4;
  #pragma unroll
  for (int j = 0; j < 4; j++)
    y[j] = (y[j] - mu) * rstd * w[col + j] + bias[col + j];
  if (OUTF32) {
    float4 o = {y[0], y[1], y[2], y[3]};
    ((float4*)out)[(size_t)row * (DD/4) + tid] = o;
  } else {
    ushort4 o = make_ushort4(f2bf(y[0]), f2bf(y[1]), f2bf(y[2]), f2bf(y[3]));
    ((ushort4*)out)[(size_t)row * (DD/4) + tid] = o;
  }
}

// ---------------- fused GEMM: kv (1024 swizzled blocks) + latent qkv (48 blocks) ----------------
// BM=256 BN=128 BK=32, 4 waves each 128x64, k-group-major LDS [kg][row][8] (conflict-free reads)
// kv: k-half -> kvk[b*2048+n][512]; v-half -> vT[(b*8+h)*64+d][2048]
__global__ __launch_bounds__(256, 2) void gemm_fused_k(
    const u16* __restrict__ xcomp, const u16* __restrict__ WkvTf,
    u16* __restrict__ kvk, u16* __restrict__ vT,
    const float* __restrict__ bias, const int* __restrict__ cnt,
    const u16* __restrict__ lnl, const u16* __restrict__ WqkvT, u16* __restrict__ qkv) {
  __shared__ __align__(16) u16 As[4 * 256 * 8];   // [kg][row][8]
  __shared__ __align__(16) u16 Bs[4 * 128 * 8];   // [kg][row][8]
  int id = blockIdx.x;
  int tid = threadIdx.x;
  int wv = tid >> 6, lane = tid & 63;
  const u16 *A, *B;
  int m0, n0, batch = 0, ml = 0;
  bool iskv;
  if (id < 1024) {
    int xg = id & 7, t = id >> 3;          // XCD swizzle
    int mtile = xg * 16 + (t >> 3);        // 0..127
    n0 = (t & 7) * 128;
    batch = mtile >> 3;
    ml = (mtile & 7) * 256;
    if (ml >= cnt[batch]) return;
    m0 = batch * NN + ml;
    A = xcomp; B = WkvTf; iskv = true;
  } else {
    int l = id - 1024;                     // 4 mtiles x 12 ntiles
    m0 = (l / 12) * 256; n0 = (l % 12) * 128;
    A = lnl; B = WqkvT; iskv = false;
  }
  const int K = 1024;
  // staging: A row = m0+tid (4 k-chunks of 8); B row = n0+(tid&127), kg = (tid>>7)+2c
  const u16* gA = A + (size_t)(m0 + tid) * K;
  const u16* gB = B + (size_t)(n0 + (tid & 127)) * K + (tid >> 7) * 8;
  u16* lA = &As[tid * 8];
  u16* lB = &Bs[(tid >> 7) * 1024 + (tid & 127) * 8];
  int wr = wv >> 1, wc = wv & 1;
  int fr = lane & 15, fq = (lane >> 4) * 8;
  int arow0 = wr * 128 + fr;
  int brow0 = wc * 64 + fr;
  f4 acc[8][4];
  #pragma unroll
  for (int mi = 0; mi < 8; mi++)
    #pragma unroll
    for (int ni = 0; ni < 4; ni++) acc[mi][ni] = f4{0.f, 0.f, 0.f, 0.f};

  for (int k0 = 0; k0 < K; k0 += 32) {
    #pragma unroll
    for (int c = 0; c < 4; c++)
      gl_lds16(gA + k0 + c * 8, lA + c * 2048);
    #pragma unroll
    for (int c = 0; c < 2; c++)
      gl_lds16(gB + k0 + c * 16, lB + c * 2048);
    __syncthreads();
    short8 af[8], bfr[4];
    #pragma unroll
    for (int mi = 0; mi < 8; mi++)
      af[mi] = *(const short8*)&As[fq * 256 + (arow0 + mi * 16) * 8];
    #pragma unroll
    for (int ni = 0; ni < 4; ni++)
      bfr[ni] = *(const short8*)&Bs[fq * 128 + (brow0 + ni * 16) * 8];
    #pragma unroll
    for (int mi = 0; mi < 8; mi++)
      #pragma unroll
      for (int ni = 0; ni < 4; ni++)
        acc[mi][ni] = __builtin_amdgcn_mfma_f32_16x16x32_bf16(af[mi], bfr[ni], acc[mi][ni], 0, 0, 0);
    __syncthreads();
  }
  int er = (lane >> 4) * 4;
  int ec = lane & 15;
  if (iskv) {
    #pragma unroll
    for (int mi = 0; mi < 8; mi++) {
      int rbase = wr * 128 + mi * 16 + er;
      #pragma unroll
      for (int ni = 0; ni < 4; ni++) {
        int col = n0 + wc * 64 + ni * 16 + ec;
        float bv = bias[col];
        if (col < 512) {
          #pragma unroll
          for (int r = 0; r < 4; r++)
            kvk[(size_t)(m0 + rbase + r) * 512 + col] = f2bf(acc[mi][ni][r] + bv);
        } else {
          int d = col - 512;
          int hh = d >> 6, dl = d & 63;
          ushort4 o4;
          o4.x = f2bf(acc[mi][ni][0] + bv);
          o4.y = f2bf(acc[mi][ni][1] + bv);
          o4.z = f2bf(acc[mi][ni][2] + bv);
          o4.w = f2bf(acc[mi][ni][3] + bv);
          *(ushort4*)(vT + ((size_t)((batch * 8 + hh) * 64 + dl)) * NN + (ml + rbase)) = o4;
        }
      }
    }
  } else {
    #pragma unroll
    for (int mi = 0; mi < 8; mi++) {
      int rbase = wr * 128 + mi * 16 + er;
      #pragma unroll
      for (int ni = 0; ni < 4; ni++) {
        int col = n0 + wc * 64 + ni * 16 + ec;
        #pragma unroll
        for (int r = 0; r < 4; r++)
          qkv[(size_t)(m0 + rbase + r) * 1536 + col] = f2bf(acc[mi][ni][r]);
      }
    }
  }
}

// ---------------- GEMM 128x64 gelu epilogue (W1: M=1024 N=4096 K=1024) ----------------
__global__ __launch_bounds__(256) void gemm_gelu_k(const u16* __restrict__ A, const u16* __restrict__ Bm,
    u16* __restrict__ C, int M, int N, int K) {
  __shared__ __align__(16) u16 As[128 * 32];
  __shared__ __align__(16) u16 Bs[64 * 32];
  int tid = threadIdx.x;
  int wv = tid >> 6, lane = tid & 63;
  int m0 = blockIdx.y * 128, n0 = blockIdx.x * 64;
  int srow = wv * 16 + (lane >> 2);
  int scol = (lane & 3) * 8;
  const u16* gA0 = A + (size_t)(m0 + srow) * K + scol;
  const u16* gA1 = A + (size_t)(m0 + 64 + srow) * K + scol;
  const u16* gB0 = Bm + (size_t)(n0 + srow) * K + scol;
  u16* lA0 = &As[srow * 32 + scol];
  u16* lA1 = &As[(64 + srow) * 32 + scol];
  u16* lB0 = &Bs[srow * 32 + scol];
  int wm = (wv & 1) * 64, wn = (wv >> 1) * 32;
  int fr = lane & 15, fq = (lane >> 4) * 8;
  f4 acc[4][2];
  #pragma unroll
  for (int mi = 0; mi < 4; mi++)
    #pragma unroll
    for (int ni = 0; ni < 2; ni++) acc[mi][ni] = f4{0.f, 0.f, 0.f, 0.f};

  for (int k0 = 0; k0 < K; k0 += 32) {
    gl_lds16(gA0 + k0, lA0);
    gl_lds16(gA1 + k0, lA1);
    gl_lds16(gB0 + k0, lB0);
    __syncthreads();
    short8 af[4], bfr[2];
    #pragma unroll
    for (int mi = 0; mi < 4; mi++)
      af[mi] = *(const short8*)&As[(wm + mi*16 + fr) * 32 + fq];
    #pragma unroll
    for (int ni = 0; ni < 2; ni++)
      bfr[ni] = *(const short8*)&Bs[(wn + ni*16 + fr) * 32 + fq];
    #pragma unroll
    for (int mi = 0; mi < 4; mi++)
      #pragma unroll
      for (int ni = 0; ni < 2; ni++)
        acc[mi][ni] = __builtin_amdgcn_mfma_f32_16x16x32_bf16(af[mi], bfr[ni], acc[mi][ni], 0, 0, 0);
    __syncthreads();
  }
  int er = (lane >> 4) * 4;
  int ec = lane & 15;
  #pragma unroll
  for (int mi = 0; mi < 4; mi++)
    #pragma unroll
    for (int ni = 0; ni < 2; ni++) {
      int col = n0 + wn + ni*16 + ec;
      #pragma unroll
      for (int r = 0; r < 4; r++) {
        int row = m0 + wm + mi*16 + er + r;
        float v = acc[mi][ni][r];
        v = 0.5f * v * (1.f + erff(v * 0.70710678118654752f));
        C[(size_t)row * N + col] = f2bf(v);
      }
    }
}

// ---------------- split-K GEMM 128x64, fp32 atomicAdd epilogue (C pre-holds residual) ----------------
__global__ __launch_bounds__(256) void gemmsk_k(const u16* __restrict__ A, const u16* __restrict__ Bm,
    float* __restrict__ C, int M, int N, int K, int Kc) {
  __shared__ __align__(16) u16 As[128 * 32];
  __shared__ __align__(16) u16 Bs[64 * 32];
  int tid = threadIdx.x;
  int wv = tid >> 6, lane = tid & 63;
  int m0 = blockIdx.y * 128, n0 = blockIdx.x * 64;
  int kb = blockIdx.z * Kc;
  int srow = wv * 16 + (lane >> 2);
  int scol = (lane & 3) * 8;
  const u16* gA0 = A + (size_t)(m0 + srow) * K + kb + scol;
  const u16* gA1 = A + (size_t)(m0 + 64 + srow) * K + kb + scol;
  const u16* gB0 = Bm + (size_t)(n0 + srow) * K + kb + scol;
  u16* lA0 = &As[srow * 32 + scol];
  u16* lA1 = &As[(64 + srow) * 32 + scol];
  u16* lB0 = &Bs[srow * 32 + scol];
  int wm = (wv & 1) * 64, wn = (wv >> 1) * 32;
  int fr = lane & 15, fq = (lane >> 4) * 8;
  f4 acc[4][2];
  #pragma unroll
  for (int mi = 0; mi < 4; mi++)
    #pragma unroll
    for (int ni = 0; ni < 2; ni++) acc[mi][ni] = f4{0.f, 0.f, 0.f, 0.f};

  for (int k0 = 0; k0 < Kc; k0 += 32) {
    gl_lds16(gA0 + k0, lA0);
    gl_lds16(gA1 + k0, lA1);
    gl_lds16(gB0 + k0, lB0);
    __syncthreads();
    short8 af[4], bfr[2];
    #pragma unroll
    for (int mi = 0; mi < 4; mi++)
      af[mi] = *(const short8*)&As[(wm + mi*16 + fr) * 32 + fq];
    #pragma unroll
    for (int ni = 0; ni < 2; ni++)
      bfr[ni] = *(const short8*)&Bs[(wn + ni*16 + fr) * 32 + fq];
    #pragma unroll
    for (int mi = 0; mi < 4; mi++)
      #pragma unroll
      for (int ni = 0; ni < 2; ni++)
        acc[mi][ni] = __builtin_amdgcn_mfma_f32_16x16x32_bf16(af[mi], bfr[ni], acc[mi][ni], 0, 0, 0);
    __syncthreads();
  }
  int er = (lane >> 4) * 4;
  int ec = lane & 15;
  #pragma unroll
  for (int mi = 0; mi < 4; mi++)
    #pragma unroll
    for (int ni = 0; ni < 2; ni++) {
      int col = n0 + wn + ni*16 + ec;
      #pragma unroll
      for (int r = 0; r < 4; r++) {
        int row = m0 + wm + mi*16 + er + r;
        atomicAdd(&C[(size_t)row * N + col], acc[mi][ni][r]);
      }
    }
}

// ---------------- flash attention, split over keys: 4 blocks per (b,h) ----------------
// qkv: [1024][1536] = [q(512) | k_lat(512) | v_lat(512)]
// kvk: compacted K [16*2048][512]; vT: pre-transposed V [(b*8+h)*64+d][2048]
__global__ __launch_bounds__(256) void attn_part_k(const u16* __restrict__ qkv,
    const u16* __restrict__ kvk, const u16* __restrict__ vT, const int* __restrict__ cnt,
    float* __restrict__ opart, float* __restrict__ mlpart) {
  int id = blockIdx.x;          // 512
  int b = id >> 5;
  int h = (id >> 2) & 7;
  int part = id & 3;
  int tid = threadIdx.x;
  int wv = tid >> 6, lane = tid & 63;
  int fr = lane & 15, fq8 = (lane >> 4) * 8;
  int c = cnt[b];
  int nt = (c + 63) >> 6;       // x-key tiles; tile nt is the latent tile
  int T = nt + 1;
  int t0 = (T * part) >> 2;
  int t1 = (T * (part + 1)) >> 2;

  __shared__ __align__(16) u16 ks[64 * 88];
  __shared__ __align__(16) u16 vs[64 * 88];
  __shared__ __align__(16) u16 ps[4][16 * 88];
  __shared__ float smask[64];

  const u16* qp = qkv + (size_t)(b * LL + wv * 16 + fr) * 1536 + h * DHD;
  short8 aq0 = *(const short8*)(qp + fq8);
  short8 aq1 = *(const short8*)(qp + 32 + fq8);

  float m_i[4], l_i[4];
  f4 o[4];
  #pragma unroll
  for (int r = 0; r < 4; r++) { m_i[r] = -1e30f; l_i[r] = 0.f; }
  #pragma unroll
  for (int dt = 0; dt < 4; dt++) o[dt] = f4{0.f, 0.f, 0.f, 0.f};

  const float scale = 0.125f;

  for (int t = t0; t < t1; t++) {
    bool isLat = (t == nt);
    __syncthreads();
    if (isLat) {
      const u16* src = qkv + (size_t)(b * LL) * 1536 + 512 + h * DHD;
      #pragma unroll
      for (int it = 0; it < 2; it++) {
        int cid = it * 256 + tid;
        int kr = cid >> 3, c8 = (cid & 7) * 8;
        int4 kvv = *(const int4*)(src + (size_t)kr * 1536 + c8);
        *(int4*)&ks[kr * 88 + c8] = kvv;
        int4 vvv = *(const int4*)(src + 512 + (size_t)kr * 1536 + c8);
        const u16* ve = (const u16*)&vvv;
        #pragma unroll
        for (int j = 0; j < 8; j++) vs[(c8 + j) * 88 + kr] = ve[j];
      }
    } else {
      const u16* ksrc = kvk + (size_t)(b * NN + t * 64) * 512 + h * DHD;
      const u16* vsrc = vT + (size_t)((b * 8 + h) * 64) * NN + t * 64;
      #pragma unroll
      for (int it = 0; it < 2; it++) {
        int cid = it * 256 + tid;
        int kr = cid >> 3, c8 = (cid & 7) * 8;
        *(int4*)&ks[kr * 88 + c8] = *(const int4*)(ksrc + (size_t)kr * 512 + c8);
        *(int4*)&vs[kr * 88 + c8] = *(const int4*)(vsrc + (size_t)kr * NN + c8);
      }
    }
    if (tid < 64)
      smask[tid] = (isLat || (t * 64 + tid < c)) ? 0.f : -1e30f;
    __syncthreads();

    f4 sim[4];
    #pragma unroll
    for (int ct = 0; ct < 4; ct++) {
      short8 b0 = *(const short8*)&ks[(ct*16 + fr) * 88 + fq8];
      short8 b1 = *(const short8*)&ks[(ct*16 + fr) * 88 + 32 + fq8];
      f4 s = f4{0.f, 0.f, 0.f, 0.f};
      s = __builtin_amdgcn_mfma_f32_16x16x32_bf16(aq0, b0, s, 0, 0, 0);
      s = __builtin_amdgcn_mfma_f32_16x16x32_bf16(aq1, b1, s, 0, 0, 0);
      float mk = smask[ct*16 + fr];
      #pragma unroll
      for (int r = 0; r < 4; r++) s[r] = s[r] * scale + mk;
      sim[ct] = s;
    }
    float mnew[4], alpha[4], p[4][4];
    #pragma unroll
    for (int r = 0; r < 4; r++) {
      float mx = fmaxf(fmaxf(sim[0][r], sim[1][r]), fmaxf(sim[2][r], sim[3][r]));
      #pragma unroll
      for (int off = 8; off >= 1; off >>= 1) mx = fmaxf(mx, __shfl_xor(mx, off, 16));
      mnew[r] = fmaxf(m_i[r], mx);
      alpha[r] = __expf(m_i[r] - mnew[r]);
      m_i[r] = mnew[r];
      float ssum = 0.f;
      #pragma unroll
      for (int ct = 0; ct < 4; ct++) { float e = __expf(sim[ct][r] - mnew[r]); p[ct][r] = e; ssum += e; }
      #pragma unroll
      for (int off = 8; off >= 1; off >>= 1) ssum += __shfl_xor(ssum, off, 16);
      l_i[r] = l_i[r] * alpha[r] + ssum;
    }
    #pragma unroll
    for (int ct = 0; ct < 4; ct++)
      #pragma unroll
      for (int r = 0; r < 4; r++)
        ps[wv][((lane>>4)*4 + r) * 88 + ct*16 + fr] = f2bf(p[ct][r]);
    #pragma unroll
    for (int dt = 0; dt < 4; dt++)
      #pragma unroll
      for (int r = 0; r < 4; r++) o[dt][r] *= alpha[r];
    short8 pa0 = *(const short8*)&ps[wv][fr * 88 + fq8];
    short8 pa1 = *(const short8*)&ps[wv][fr * 88 + 32 + fq8];
    #pragma unroll
    for (int dt = 0; dt < 4; dt++) {
      short8 bv0 = *(const short8*)&vs[(dt*16 + fr) * 88 + fq8];
      short8 bv1 = *(const short8*)&vs[(dt*16 + fr) * 88 + 32 + fq8];
      o[dt] = __builtin_amdgcn_mfma_f32_16x16x32_bf16(pa0, bv0, o[dt], 0, 0, 0);
      o[dt] = __builtin_amdgcn_mfma_f32_16x16x32_bf16(pa1, bv1, o[dt], 0, 0, 0);
    }
  }
  #pragma unroll
  for (int dt = 0; dt < 4; dt++)
    #pragma unroll
    for (int r = 0; r < 4; r++) {
      int row = wv * 16 + (lane>>4)*4 + r;
      int col = dt*16 + fr;
      opart[((size_t)id * 64 + row) * 64 + col] = o[dt][r];
    }
  if (fr == 0) {
    #pragma unroll
    for (int r = 0; r < 4; r++) {
      int row = wv * 16 + (lane>>4)*4 + r;
      mlpart[id * 128 + row * 2]     = m_i[r];
      mlpart[id * 128 + row * 2 + 1] = l_i[r];
    }
  }
}

// ---------------- combine the four key-parts ----------------
__global__ __launch_bounds__(256) void attn_comb_k(const float* __restrict__ opart,
    const float* __restrict__ mlpart, u16* __restrict__ out) {
  int bh = blockIdx.x;          // 128
  int b = bh >> 3, h = bh & 7;
  int tid = threadIdx.x;
  int row = tid >> 2;
  int c0 = (tid & 3) * 16;
  float mp[4], lp[4];
  float m = -1e30f;
  #pragma unroll
  for (int p = 0; p < 4; p++) {
    mp[p] = mlpart[(bh * 4 + p) * 128 + row * 2];
    lp[p] = mlpart[(bh * 4 + p) * 128 + row * 2 + 1];
    m = fmaxf(m, mp[p]);
  }
  float a[4]; float L = 0.f;
  #pragma unroll
  for (int p = 0; p < 4; p++) { a[p] = __expf(mp[p] - m); L += lp[p] * a[p]; }
  float rl = 1.f / L;
  u16* op = out + ((size_t)(b * LL + row)) * II + h * DHD + c0;
  #pragma unroll
  for (int j = 0; j < 4; j++) {
    float acc4[4] = {0.f, 0.f, 0.f, 0.f};
    #pragma unroll
    for (int p = 0; p < 4; p++) {
      const float4* pp = (const float4*)(opart + ((size_t)(bh * 4 + p) * 64 + row) * 64 + c0);
      float4 v = pp[j];
      acc4[0] += v.x * a[p]; acc4[1] += v.y * a[p];
      acc4[2] += v.z * a[p]; acc4[3] += v.w * a[p];
    }
    op[j*4 + 0] = f2bf(acc4[0] * rl);
    op[j*4 + 1] = f2bf(acc4[1] * rl);
    op[j*4 + 2] = f2bf(acc4[2] * rl);
    op[j*4 + 3] = f2bf(acc4[3] * rl);
  }
}

extern "C" void kernel_launch(void* const* d_in, const int* in_sizes, int n_in,
                              void* d_out, int out_size, void* d_ws, size_t ws_size,
                              hipStream_t stream) {
  (void)in_sizes; (void)n_in; (void)out_size; (void)ws_size;
  const float* x       = (const float*)d_in[0];
  const int*   mask    = (const int*)d_in[1];
  const float* latents = (const float*)d_in[2];
  const float* ln_m_w  = (const float*)d_in[3];
  const float* ln_m_b  = (const float*)d_in[4];
  const float* ln_l_w  = (const float*)d_in[5];
  const float* ln_l_b  = (const float*)d_in[6];
  const float* Wq      = (const float*)d_in[7];
  const float* Wkv     = (const float*)d_in[8];
  const float* Wo      = (const float*)d_in[9];
  const float* ff_ln_w = (const float*)d_in[10];
  const float* ff_ln_b = (const float*)d_in[11];
  const float* W1      = (const float*)d_in[12];
  const float* W2      = (const float*)d_in[13];
  const float* norm_w  = (const float*)d_in[14];
  const float* norm_b  = (const float*)d_in[15];
  float* out = (float*)d_out;

  char* ws = (char*)d_ws;
  size_t off = 0;
  auto alloc = [&](size_t bytes) -> void* {
    void* p = ws + off; off += (bytes + 255) & ~(size_t)255; return p;
  };
  u16* xcomp = (u16*)alloc((size_t)32768 * 1024 * 2);
  u16* kvk   = (u16*)alloc((size_t)32768 * 512 * 2);
  u16* vT    = (u16*)alloc((size_t)8192 * 2048 * 2);
  int* idxb  = (int*)alloc((size_t)32768 * 4);
  int* cnt   = (int*)alloc(64);
  float* lat = (float*)alloc((size_t)1024 * 1024 * 4);
  u16* lnl   = (u16*)alloc((size_t)1024 * 1024 * 2);
  u16* latn  = (u16*)alloc((size_t)1024 * 1024 * 2);
  u16* qkv   = (u16*)alloc((size_t)1024 * 1536 * 2);
  u16* aout  = (u16*)alloc((size_t)1024 * 512 * 2);
  u16* hf    = (u16*)alloc((size_t)1024 * 4096 * 2);
  float* opart  = (float*)alloc((size_t)512 * 64 * 64 * 4);
  float* mlpart = (float*)alloc((size_t)512 * 128 * 4);
  u16* WqkvT = (u16*)alloc((size_t)DEPTHC * 1536 * 1024 * 2);
  u16* WkvTf = (u16*)alloc((size_t)DEPTHC * 1024 * 1024 * 2);
  u16* WoT   = (u16*)alloc((size_t)DEPTHC * 1024 * 512 * 2);
  u16* W1T   = (u16*)alloc((size_t)DEPTHC * 4096 * 1024 * 2);
  u16* W2T   = (u16*)alloc((size_t)DEPTHC * 1024 * 4096 * 2);
  float* biaskv_all = (float*)alloc(DEPTHC * 1024 * 4);

  // pre-loop: compaction + bias zero, then W1/W2 transposes, then fused qkvo+LN-gather+lat-init
  maskscan_k<<<16, 256, 0, stream>>>(mask, idxb, cnt);
  zero_k<<<24, 256, 0, stream>>>(biaskv_all, DEPTHC * 1024);
  transp_w_k<<<DEPTHC * 1024, 256, 0, stream>>>(W1, W1T, 1024, 4096, 6);
  transp_w_k<<<DEPTHC * 1024, 256, 0, stream>>>(W2, W2T, 4096, 1024, 4);
  qkvo_fused_k<<<3072 + 32768 + 1024, 256, 0, stream>>>(
      Wq, Wkv, Wo, ln_m_w, ln_m_b,
      WqkvT, WoT, WkvTf, biaskv_all,
      x, idxb, cnt, xcomp, latents, lat);

  for (int i = 0; i < DEPTHC; i++) {
    ln_rows_k<false><<<1024, 256, 0, stream>>>(lat, ln_l_w + i*1024, ln_l_b + i*1024, lnl);
    gemm_fused_k<<<1072, 256, 0, stream>>>(
        xcomp, WkvTf + (size_t)i*1024*1024, kvk, vT, biaskv_all + i*1024, cnt,
        lnl, WqkvT + (size_t)i*1536*1024, qkv);
    attn_part_k<<<512, 256, 0, stream>>>(qkv, kvk, vT, cnt, opart, mlpart);
    attn_comb_k<<<128, 256, 0, stream>>>(opart, mlpart, aout);
    gemmsk_k<<<dim3(16, 8, 4), 256, 0, stream>>>(aout, WoT + (size_t)i*1024*512, lat, 1024, 1024, 512, 128);
    ln_rows_k<false><<<1024, 256, 0, stream>>>(lat, ff_ln_w + i*1024, ff_ln_b + i*1024, latn);
    gemm_gelu_k<<<dim3(64, 8), 256, 0, stream>>>(latn, W1T + (size_t)i*4096*1024, hf, 1024, 4096, 1024);
    gemmsk_k<<<dim3(16, 8, 4), 256, 0, stream>>>(hf, W2T + (size_t)i*1024*4096, lat, 1024, 1024, 4096, 1024);
  }
  ln_rows_k<true><<<1024, 256, 0, stream>>>(lat, norm_w, norm_b, out);
}

// Round 10
// 1439.366 us; speedup vs baseline: 1.1603x; 1.1603x over previous
//
#include <hip/hip_runtime.h>

typedef unsigned short u16;
typedef unsigned int u32;
typedef __attribute__((ext_vector_type(8))) short short8;
typedef __attribute__((ext_vector_type(4))) float f4;

#define DEV static __device__ __forceinline__

constexpr int BB = 16, NN = 2048, DD = 1024, HH = 8, DHD = 64, II = 512, LL = 64, DEPTHC = 6, FFC = 4096;

DEV u16 f2bf(float f) {
  union { float f; u32 u; } v; v.f = f;
  u32 r = v.u + 0x7FFFu + ((v.u >> 16) & 1u);
  return (u16)(r >> 16);
}

DEV u32 pack2(float lo, float hi) {
  return (u32)f2bf(lo) | ((u32)f2bf(hi) << 16);
}

typedef const u32 __attribute__((address_space(1)))* gas_p;
typedef u32 __attribute__((address_space(3)))* las_p;
DEV void gl_lds16(const void* g, void* l) {
  __builtin_amdgcn_global_load_lds((gas_p)g, (las_p)l, 16, 0, 0);
}

// ---------------- mask prefix-scan: per batch, list of unmasked (mask==0) indices ----------------
__global__ __launch_bounds__(256) void maskscan_k(const int* __restrict__ mask,
    int* __restrict__ idx, int* __restrict__ cnt) {
  int b = blockIdx.x, tid = threadIdx.x;
  int lane = tid & 63, wv = tid >> 6;
  const int* mrow = mask + (size_t)b * NN;
  int base = tid * 8;
  int keep[8]; int local = 0;
  #pragma unroll
  for (int j = 0; j < 8; j++) { keep[j] = (mrow[base + j] == 0); local += keep[j]; }
  int incl = local;
  #pragma unroll
  for (int off = 1; off < 64; off <<= 1) {
    int v = __shfl_up(incl, off, 64);
    if (lane >= off) incl += v;
  }
  __shared__ int wsum[4];
  if (lane == 63) wsum[wv] = incl;
  __syncthreads();
  int wbase = 0;
  for (int w = 0; w < wv; w++) wbase += wsum[w];
  int pos = wbase + incl - local;
  #pragma unroll
  for (int j = 0; j < 8; j++) if (keep[j]) idx[(size_t)b * NN + pos++] = base + j;
  if (tid == 255) cnt[b] = wbase + incl;
}

// ---------------- zero small buffer ----------------
__global__ void zero_k(float* __restrict__ p, int n) {
  int i = blockIdx.x * 256 + threadIdx.x;
  if (i < n) p[i] = 0.f;
}

// ---------------- W1 / W2 transpose: 64x64 tiles, 1024 tiles per depth ----------------
__global__ __launch_bounds__(256) void transp_w_k(const float* __restrict__ Wa, u16* __restrict__ WTa,
    int R, int C, int ctLog) {
  __shared__ float t[64][65];
  int gid = blockIdx.x;
  int depth = gid >> 10;
  int l = gid & 1023;
  int c0 = (l & ((1 << ctLog) - 1)) << 6;
  int r0 = (l >> ctLog) << 6;
  const float* in = Wa + (size_t)depth * 4096 * 1024;
  u16* o1 = WTa + (size_t)depth * 4096 * 1024;
  int tid = threadIdx.x;
  int lr = tid >> 4, lc4 = (tid & 15) * 4;
  #pragma unroll
  for (int p = 0; p < 4; p++) {
    int row = p * 16 + lr;
    float4 v = *(const float4*)&in[(size_t)(r0 + row) * C + c0 + lc4];
    t[row][lc4] = v.x; t[row][lc4+1] = v.y; t[row][lc4+2] = v.z; t[row][lc4+3] = v.w;
  }
  __syncthreads();
  int oc = tid >> 3;
  int rg = tid & 7;
  #pragma unroll
  for (int p = 0; p < 2; p++) {
    int c = p * 32 + oc;
    float v[8];
    #pragma unroll
    for (int k = 0; k < 8; k++) v[k] = t[rg * 8 + k][c];
    int4 o;
    o.x = (int)pack2(v[0], v[1]); o.y = (int)pack2(v[2], v[3]);
    o.z = (int)pack2(v[4], v[5]); o.w = (int)pack2(v[6], v[7]);
    *(int4*)&o1[(size_t)(c0 + c) * R + r0 + rg * 8] = o;
  }
}

// ---------------- fused pre-pass: Wq/Wkv/Wo transposes (+kv fold) | LN-gather | lat-init ----------
__global__ __launch_bounds__(256) void qkvo_fused_k(
    const float* __restrict__ WqA, const float* __restrict__ WkvA, const float* __restrict__ WoA,
    const float* __restrict__ lnwA, const float* __restrict__ lnbA,
    u16* __restrict__ WqkvTA, u16* __restrict__ WoTA, u16* __restrict__ WkvTfA,
    float* __restrict__ biaskvA,
    const float* __restrict__ x, const int* __restrict__ idx, const int* __restrict__ cnt,
    u16* __restrict__ xcomp, const float* __restrict__ latents, float* __restrict__ lat) {
  __shared__ float t[64][65];
  __shared__ float red8[8];
  int gid = blockIdx.x;
  int tid = threadIdx.x;
  if (gid < 3072) {
    int depth = gid >> 9;
    int id = gid & 511;
    const float* in; u16* o1; int R, C, c0, r0;
    bool iskv = false;
    if (id < 128)      { in = WqA  + (size_t)depth*1024*512;  R = 1024; C = 512;  int l = id;       c0 = (l & 7) * 64;  r0 = (l >> 3) * 64; o1 = WqkvTA + (size_t)depth*1536*1024; }
    else if (id < 384) { in = WkvA + (size_t)depth*1024*1024; R = 1024; C = 1024; int l = id - 128; c0 = (l & 15) * 64; r0 = (l >> 4) * 64; o1 = WqkvTA + (size_t)depth*1536*1024 + 512*1024; iskv = true; }
    else               { in = WoA  + (size_t)depth*512*1024;  R = 512;  C = 1024; int l = id - 384; c0 = (l & 15) * 64; r0 = (l >> 4) * 64; o1 = WoTA + (size_t)depth*1024*512; }
    int lr = tid >> 4, lc4 = (tid & 15) * 4;
    #pragma unroll
    for (int p = 0; p < 4; p++) {
      int row = p * 16 + lr;
      float4 v = *(const float4*)&in[(size_t)(r0 + row) * C + c0 + lc4];
      t[row][lc4] = v.x; t[row][lc4+1] = v.y; t[row][lc4+2] = v.z; t[row][lc4+3] = v.w;
    }
    int oc = tid >> 3;
    int rg = tid & 7;
    float lw[8], lb[8];
    if (iskv) {
      const float* lnw = lnwA + depth * 1024;
      const float* lnb = lnbA + depth * 1024;
      int rbase = r0 + rg * 8;
      float4 w0 = *(const float4*)&lnw[rbase];
      float4 w1 = *(const float4*)&lnw[rbase + 4];
      float4 b0 = *(const float4*)&lnb[rbase];
      float4 b1 = *(const float4*)&lnb[rbase + 4];
      lw[0]=w0.x; lw[1]=w0.y; lw[2]=w0.z; lw[3]=w0.w; lw[4]=w1.x; lw[5]=w1.y; lw[6]=w1.z; lw[7]=w1.w;
      lb[0]=b0.x; lb[1]=b0.y; lb[2]=b0.z; lb[3]=b0.w; lb[4]=b1.x; lb[5]=b1.y; lb[6]=b1.z; lb[7]=b1.w;
    }
    __syncthreads();
    #pragma unroll
    for (int p = 0; p < 2; p++) {
      int c = p * 32 + oc;
      float v[8];
      #pragma unroll
      for (int k = 0; k < 8; k++) v[k] = t[rg * 8 + k][c];
      int4 o;
      o.x = (int)pack2(v[0], v[1]); o.y = (int)pack2(v[2], v[3]);
      o.z = (int)pack2(v[4], v[5]); o.w = (int)pack2(v[6], v[7]);
      *(int4*)&o1[(size_t)(c0 + c) * R + r0 + rg * 8] = o;
      if (iskv) {
        u16* WkvTf = WkvTfA + (size_t)depth*1024*1024;
        int4 of;
        of.x = (int)pack2(v[0]*lw[0], v[1]*lw[1]); of.y = (int)pack2(v[2]*lw[2], v[3]*lw[3]);
        of.z = (int)pack2(v[4]*lw[4], v[5]*lw[5]); of.w = (int)pack2(v[6]*lw[6], v[7]*lw[7]);
        *(int4*)&WkvTf[(size_t)(c0 + c) * 1024 + r0 + rg * 8] = of;
        float partial = 0.f;
        #pragma unroll
        for (int k = 0; k < 8; k++) partial += lb[k] * v[k];
        partial += __shfl_xor(partial, 1, 64);
        partial += __shfl_xor(partial, 2, 64);
        partial += __shfl_xor(partial, 4, 64);
        if (rg == 0) atomicAdd(&biaskvA[depth*1024 + c0 + c], partial);
      }
    }
    return;
  }
  gid -= 3072;
  if (gid < 32768) {
    // ---- ln_gather (zero-pad to 256-row alignment) ----
    int b = gid >> 11, j = gid & 2047;
    int c = cnt[b];
    if (j >= ((c + 255) & ~255)) return;
    ushort4* orow = (ushort4*)(xcomp + ((size_t)b * NN + j) * DD);
    if (j >= c) { orow[tid] = make_ushort4(0, 0, 0, 0); return; }
    int src = idx[(size_t)b * NN + j];
    const float4* rp = (const float4*)(x + ((size_t)b * NN + src) * DD);
    float4 v = rp[tid];
    float s = v.x + v.y + v.z + v.w;
    float s2 = v.x*v.x + v.y*v.y + v.z*v.z + v.w*v.w;
    #pragma unroll
    for (int off = 32; off >= 1; off >>= 1) {
      s  += __shfl_xor(s, off, 64);
      s2 += __shfl_xor(s2, off, 64);
    }
    int wv = tid >> 6;
    if ((tid & 63) == 0) { red8[wv] = s; red8[4 + wv] = s2; }
    __syncthreads();
    s  = red8[0] + red8[1] + red8[2] + red8[3];
    s2 = red8[4] + red8[5] + red8[6] + red8[7];
    float mu = s * (1.f / DD);
    float var = s2 * (1.f / DD) - mu * mu;
    float rstd = rsqrtf(var + 1e-5f);
    orow[tid] = make_ushort4(f2bf((v.x - mu) * rstd), f2bf((v.y - mu) * rstd),
                             f2bf((v.z - mu) * rstd), f2bf((v.w - mu) * rstd));
    return;
  }
  gid -= 32768;
  // ---- lat_init ----
  int i2 = gid * 256 + tid;
  ((float4*)lat)[i2] = ((const float4*)latents)[i2 & (LL * DD / 4 - 1)];
}

// ---------------- LayerNorm over rows of 1024 (latent path) ----------------
template<bool OUTF32>
__global__ __launch_bounds__(256) void ln_rows_k(const float* __restrict__ in,
    const float* __restrict__ w, const float* __restrict__ bias, void* __restrict__ out) {
  int row = blockIdx.x;
  int tid = threadIdx.x;
  const float4* rp = (const float4*)(in + (size_t)row * DD);
  float4 x = rp[tid];
  float s = x.x + x.y + x.z + x.w;
  float s2 = x.x*x.x + x.y*x.y + x.z*x.z + x.w*x.w;
  #pragma unroll
  for (int off = 32; off >= 1; off >>= 1) {
    s  += __shfl_xor(s, off, 64);
    s2 += __shfl_xor(s2, off, 64);
  }
  __shared__ float red[8];
  int wv = tid >> 6;
  if ((tid & 63) == 0) { red[wv] = s; red[4 + wv] = s2; }
  __syncthreads();
  s  = red[0] + red[1] + red[2] + red[3];
  s2 = red[4] + red[5] + red[6] + red[7];
  float mu = s * (1.f / DD);
  float var = s2 * (1.f / DD) - mu * mu;
  float rstd = rsqrtf(var + 1e-5f);
  float y[4] = {x.x, x.y, x.z, x.w};
  int col = tid * 4;
  #pragma unroll
  for (int j = 0; j < 4; j++)
    y[j] = (y[j] - mu) * rstd * w[col + j] + bias[col + j];
  if (OUTF32) {
    float4 o = {y[0], y[1], y[2], y[3]};
    ((float4*)out)[(size_t)row * (DD/4) + tid] = o;
  } else {
    ushort4 o = make_ushort4(f2bf(y[0]), f2bf(y[1]), f2bf(y[2]), f2bf(y[3]));
    ((ushort4*)out)[(size_t)row * (DD/4) + tid] = o;
  }
}

// ---------------- fused GEMM launch: kv (2048 swizzled blocks) + latent qkv (96 blocks) ----------
// 128x128 tile, BK=32. LDS chunk-XOR swizzle: slot (r,c) holds global chunk c^((r>>1)&3);
// store side pre-swizzles the GLOBAL source (LDS dst stays linear for global_load_lds).
__global__ __launch_bounds__(256) void gemm_fused_k(
    const u16* __restrict__ xcomp, const u16* __restrict__ WkvTf,
    u16* __restrict__ kvk, u16* __restrict__ vT,
    const float* __restrict__ bias, const int* __restrict__ cnt,
    const u16* __restrict__ lnl, const u16* __restrict__ WqkvT, u16* __restrict__ qkv) {
  __shared__ __align__(16) u16 As[128 * 32];
  __shared__ __align__(16) u16 Bs[128 * 32];
  int id = blockIdx.x;
  int tid = threadIdx.x;
  int wv = tid >> 6, lane = tid & 63;
  const u16 *A, *B;
  int m0, n0, batch = 0, ml = 0;
  bool iskv;
  if (id < 2048) {
    int xg = id & 7, t = id >> 3;
    int mtile = xg * 32 + (t >> 3);
    n0 = (t & 7) * 128;
    batch = mtile >> 4;
    ml = (mtile & 15) * 128;
    if (ml >= cnt[batch]) return;
    m0 = batch * NN + ml;
    A = xcomp; B = WkvTf; iskv = true;
  } else {
    int l = id - 2048;            // 8 mtiles x 12 ntiles
    m0 = (l / 12) * 128; n0 = (l % 12) * 128;
    A = lnl; B = WqkvT; iskv = false;
  }
  const int K = 1024;
  int srow = wv * 16 + (lane >> 2);
  int sg = (((lane & 3) ^ ((lane >> 3) & 3))) * 8;  // swizzled global chunk offset
  int sl = (lane & 3) * 8;                           // linear LDS chunk offset
  const u16* gA0 = A + (size_t)(m0 + srow) * K + sg;
  const u16* gA1 = A + (size_t)(m0 + 64 + srow) * K + sg;
  const u16* gB0 = B + (size_t)(n0 + srow) * K + sg;
  const u16* gB1 = B + (size_t)(n0 + 64 + srow) * K + sg;
  u16* lA0 = &As[srow * 32 + sl];
  u16* lA1 = &As[(64 + srow) * 32 + sl];
  u16* lB0 = &Bs[srow * 32 + sl];
  u16* lB1 = &Bs[(64 + srow) * 32 + sl];
  int wm = (wv & 1) * 64, wn = (wv >> 1) * 64;
  int fr = lane & 15;
  int cs = (((lane >> 4) ^ ((lane >> 1) & 3))) * 8;  // swizzled read chunk offset
  f4 acc[4][4];
  #pragma unroll
  for (int mi = 0; mi < 4; mi++)
    #pragma unroll
    for (int ni = 0; ni < 4; ni++) acc[mi][ni] = f4{0.f, 0.f, 0.f, 0.f};

  for (int k0 = 0; k0 < K; k0 += 32) {
    gl_lds16(gA0 + k0, lA0);
    gl_lds16(gA1 + k0, lA1);
    gl_lds16(gB0 + k0, lB0);
    gl_lds16(gB1 + k0, lB1);
    __syncthreads();
    short8 af[4], bfr[4];
    #pragma unroll
    for (int mi = 0; mi < 4; mi++)
      af[mi] = *(const short8*)&As[(wm + mi*16 + fr) * 32 + cs];
    #pragma unroll
    for (int ni = 0; ni < 4; ni++)
      bfr[ni] = *(const short8*)&Bs[(wn + ni*16 + fr) * 32 + cs];
    #pragma unroll
    for (int mi = 0; mi < 4; mi++)
      #pragma unroll
      for (int ni = 0; ni < 4; ni++)
        acc[mi][ni] = __builtin_amdgcn_mfma_f32_16x16x32_bf16(af[mi], bfr[ni], acc[mi][ni], 0, 0, 0);
    __syncthreads();
  }
  int er = (lane >> 4) * 4;
  int ec = lane & 15;
  if (iskv) {
    #pragma unroll
    for (int mi = 0; mi < 4; mi++) {
      int rbase = wm + mi*16 + er;
      #pragma unroll
      for (int ni = 0; ni < 4; ni++) {
        int col = n0 + wn + ni*16 + ec;
        float bv = bias[col];
        if (col < 512) {
          #pragma unroll
          for (int r = 0; r < 4; r++)
            kvk[(size_t)(m0 + rbase + r) * 512 + col] = f2bf(acc[mi][ni][r] + bv);
        } else {
          int d = col - 512;
          int hh = d >> 6, dl = d & 63;
          ushort4 o4;
          o4.x = f2bf(acc[mi][ni][0] + bv);
          o4.y = f2bf(acc[mi][ni][1] + bv);
          o4.z = f2bf(acc[mi][ni][2] + bv);
          o4.w = f2bf(acc[mi][ni][3] + bv);
          *(ushort4*)(vT + ((size_t)((batch * 8 + hh) * 64 + dl)) * NN + (ml + rbase)) = o4;
        }
      }
    }
  } else {
    #pragma unroll
    for (int mi = 0; mi < 4; mi++)
      #pragma unroll
      for (int ni = 0; ni < 4; ni++) {
        int col = n0 + wn + ni*16 + ec;
        #pragma unroll
        for (int r = 0; r < 4; r++) {
          int row = m0 + wm + mi*16 + er + r;
          qkv[(size_t)row * 1536 + col] = f2bf(acc[mi][ni][r]);
        }
      }
  }
}

// ---------------- GEMM 128x64 gelu epilogue (W1: M=1024 N=4096 K=1024), chunk-swizzled ----------
__global__ __launch_bounds__(256) void gemm_gelu_k(const u16* __restrict__ A, const u16* __restrict__ Bm,
    u16* __restrict__ C, int M, int N, int K) {
  __shared__ __align__(16) u16 As[128 * 32];
  __shared__ __align__(16) u16 Bs[64 * 32];
  int tid = threadIdx.x;
  int wv = tid >> 6, lane = tid & 63;
  int m0 = blockIdx.y * 128, n0 = blockIdx.x * 64;
  int srow = wv * 16 + (lane >> 2);
  int sg = (((lane & 3) ^ ((lane >> 3) & 3))) * 8;
  int sl = (lane & 3) * 8;
  const u16* gA0 = A + (size_t)(m0 + srow) * K + sg;
  const u16* gA1 = A + (size_t)(m0 + 64 + srow) * K + sg;
  const u16* gB0 = Bm + (size_t)(n0 + srow) * K + sg;
  u16* lA0 = &As[srow * 32 + sl];
  u16* lA1 = &As[(64 + srow) * 32 + sl];
  u16* lB0 = &Bs[srow * 32 + sl];
  int wm = (wv & 1) * 64, wn = (wv >> 1) * 32;
  int fr = lane & 15;
  int cs = (((lane >> 4) ^ ((lane >> 1) & 3))) * 8;
  f4 acc[4][2];
  #pragma unroll
  for (int mi = 0; mi < 4; mi++)
    #pragma unroll
    for (int ni = 0; ni < 2; ni++) acc[mi][ni] = f4{0.f, 0.f, 0.f, 0.f};

  for (int k0 = 0; k0 < K; k0 += 32) {
    gl_lds16(gA0 + k0, lA0);
    gl_lds16(gA1 + k0, lA1);
    gl_lds16(gB0 + k0, lB0);
    __syncthreads();
    short8 af[4], bfr[2];
    #pragma unroll
    for (int mi = 0; mi < 4; mi++)
      af[mi] = *(const short8*)&As[(wm + mi*16 + fr) * 32 + cs];
    #pragma unroll
    for (int ni = 0; ni < 2; ni++)
      bfr[ni] = *(const short8*)&Bs[(wn + ni*16 + fr) * 32 + cs];
    #pragma unroll
    for (int mi = 0; mi < 4; mi++)
      #pragma unroll
      for (int ni = 0; ni < 2; ni++)
        acc[mi][ni] = __builtin_amdgcn_mfma_f32_16x16x32_bf16(af[mi], bfr[ni], acc[mi][ni], 0, 0, 0);
    __syncthreads();
  }
  int er = (lane >> 4) * 4;
  int ec = lane & 15;
  #pragma unroll
  for (int mi = 0; mi < 4; mi++)
    #pragma unroll
    for (int ni = 0; ni < 2; ni++) {
      int col = n0 + wn + ni*16 + ec;
      #pragma unroll
      for (int r = 0; r < 4; r++) {
        int row = m0 + wm + mi*16 + er + r;
        float v = acc[mi][ni][r];
        v = 0.5f * v * (1.f + erff(v * 0.70710678118654752f));
        C[(size_t)row * N + col] = f2bf(v);
      }
    }
}

// ---------------- split-K GEMM 128x64, fp32 atomicAdd epilogue, chunk-swizzled ----------------
__global__ __launch_bounds__(256) void gemmsk_k(const u16* __restrict__ A, const u16* __restrict__ Bm,
    float* __restrict__ C, int M, int N, int K, int Kc) {
  __shared__ __align__(16) u16 As[128 * 32];
  __shared__ __align__(16) u16 Bs[64 * 32];
  int tid = threadIdx.x;
  int wv = tid >> 6, lane = tid & 63;
  int m0 = blockIdx.y * 128, n0 = blockIdx.x * 64;
  int kb = blockIdx.z * Kc;
  int srow = wv * 16 + (lane >> 2);
  int sg = (((lane & 3) ^ ((lane >> 3) & 3))) * 8;
  int sl = (lane & 3) * 8;
  const u16* gA0 = A + (size_t)(m0 + srow) * K + kb + sg;
  const u16* gA1 = A + (size_t)(m0 + 64 + srow) * K + kb + sg;
  const u16* gB0 = Bm + (size_t)(n0 + srow) * K + kb + sg;
  u16* lA0 = &As[srow * 32 + sl];
  u16* lA1 = &As[(64 + srow) * 32 + sl];
  u16* lB0 = &Bs[srow * 32 + sl];
  int wm = (wv & 1) * 64, wn = (wv >> 1) * 32;
  int fr = lane & 15;
  int cs = (((lane >> 4) ^ ((lane >> 1) & 3))) * 8;
  f4 acc[4][2];
  #pragma unroll
  for (int mi = 0; mi < 4; mi++)
    #pragma unroll
    for (int ni = 0; ni < 2; ni++) acc[mi][ni] = f4{0.f, 0.f, 0.f, 0.f};

  for (int k0 = 0; k0 < Kc; k0 += 32) {
    gl_lds16(gA0 + k0, lA0);
    gl_lds16(gA1 + k0, lA1);
    gl_lds16(gB0 + k0, lB0);
    __syncthreads();
    short8 af[4], bfr[2];
    #pragma unroll
    for (int mi = 0; mi < 4; mi++)
      af[mi] = *(const short8*)&As[(wm + mi*16 + fr) * 32 + cs];
    #pragma unroll
    for (int ni = 0; ni < 2; ni++)
      bfr[ni] = *(const short8*)&Bs[(wn + ni*16 + fr) * 32 + cs];
    #pragma unroll
    for (int mi = 0; mi < 4; mi++)
      #pragma unroll
      for (int ni = 0; ni < 2; ni++)
        acc[mi][ni] = __builtin_amdgcn_mfma_f32_16x16x32_bf16(af[mi], bfr[ni], acc[mi][ni], 0, 0, 0);
    __syncthreads();
  }
  int er = (lane >> 4) * 4;
  int ec = lane & 15;
  #pragma unroll
  for (int mi = 0; mi < 4; mi++)
    #pragma unroll
    for (int ni = 0; ni < 2; ni++) {
      int col = n0 + wn + ni*16 + ec;
      #pragma unroll
      for (int r = 0; r < 4; r++) {
        int row = m0 + wm + mi*16 + er + r;
        atomicAdd(&C[(size_t)row * N + col], acc[mi][ni][r]);
      }
    }
}

// ---------------- flash attention, split over keys: 4 blocks per (b,h) ----------------
__global__ __launch_bounds__(256) void attn_part_k(const u16* __restrict__ qkv,
    const u16* __restrict__ kvk, const u16* __restrict__ vT, const int* __restrict__ cnt,
    float* __restrict__ opart, float* __restrict__ mlpart) {
  int id = blockIdx.x;          // 512
  int b = id >> 5;
  int h = (id >> 2) & 7;
  int part = id & 3;
  int tid = threadIdx.x;
  int wv = tid >> 6, lane = tid & 63;
  int fr = lane & 15, fq8 = (lane >> 4) * 8;
  int c = cnt[b];
  int nt = (c + 63) >> 6;
  int T = nt + 1;
  int t0 = (T * part) >> 2;
  int t1 = (T * (part + 1)) >> 2;

  __shared__ __align__(16) u16 ks[64 * 88];
  __shared__ __align__(16) u16 vs[64 * 88];
  __shared__ __align__(16) u16 ps[4][16 * 88];
  __shared__ float smask[64];

  const u16* qp = qkv + (size_t)(b * LL + wv * 16 + fr) * 1536 + h * DHD;
  short8 aq0 = *(const short8*)(qp + fq8);
  short8 aq1 = *(const short8*)(qp + 32 + fq8);

  float m_i[4], l_i[4];
  f4 o[4];
  #pragma unroll
  for (int r = 0; r < 4; r++) { m_i[r] = -1e30f; l_i[r] = 0.f; }
  #pragma unroll
  for (int dt = 0; dt < 4; dt++) o[dt] = f4{0.f, 0.f, 0.f, 0.f};

  const float scale = 0.125f;

  for (int t = t0; t < t1; t++) {
    bool isLat = (t == nt);
    __syncthreads();
    if (isLat) {
      const u16* src = qkv + (size_t)(b * LL) * 1536 + 512 + h * DHD;
      #pragma unroll
      for (int it = 0; it < 2; it++) {
        int cid = it * 256 + tid;
        int kr = cid >> 3, c8 = (cid & 7) * 8;
        int4 kvv = *(const int4*)(src + (size_t)kr * 1536 + c8);
        *(int4*)&ks[kr * 88 + c8] = kvv;
        int4 vvv = *(const int4*)(src + 512 + (size_t)kr * 1536 + c8);
        const u16* ve = (const u16*)&vvv;
        #pragma unroll
        for (int j = 0; j < 8; j++) vs[(c8 + j) * 88 + kr] = ve[j];
      }
    } else {
      const u16* ksrc = kvk + (size_t)(b * NN + t * 64) * 512 + h * DHD;
      const u16* vsrc = vT + (size_t)((b * 8 + h) * 64) * NN + t * 64;
      #pragma unroll
      for (int it = 0; it < 2; it++) {
        int cid = it * 256 + tid;
        int kr = cid >> 3, c8 = (cid & 7) * 8;
        *(int4*)&ks[kr * 88 + c8] = *(const int4*)(ksrc + (size_t)kr * 512 + c8);
        *(int4*)&vs[kr * 88 + c8] = *(const int4*)(vsrc + (size_t)kr * NN + c8);
      }
    }
    if (tid < 64)
      smask[tid] = (isLat || (t * 64 + tid < c)) ? 0.f : -1e30f;
    __syncthreads();

    f4 sim[4];
    #pragma unroll
    for (int ct = 0; ct < 4; ct++) {
      short8 b0 = *(const short8*)&ks[(ct*16 + fr) * 88 + fq8];
      short8 b1 = *(const short8*)&ks[(ct*16 + fr) * 88 + 32 + fq8];
      f4 s = f4{0.f, 0.f, 0.f, 0.f};
      s = __builtin_amdgcn_mfma_f32_16x16x32_bf16(aq0, b0, s, 0, 0, 0);
      s = __builtin_amdgcn_mfma_f32_16x16x32_bf16(aq1, b1, s, 0, 0, 0);
      float mk = smask[ct*16 + fr];
      #pragma unroll
      for (int r = 0; r < 4; r++) s[r] = s[r] * scale + mk;
      sim[ct] = s;
    }
    float mnew[4], alpha[4], p[4][4];
    #pragma unroll
    for (int r = 0; r < 4; r++) {
      float mx = fmaxf(fmaxf(sim[0][r], sim[1][r]), fmaxf(sim[2][r], sim[3][r]));
      #pragma unroll
      for (int off = 8; off >= 1; off >>= 1) mx = fmaxf(mx, __shfl_xor(mx, off, 16));
      mnew[r] = fmaxf(m_i[r], mx);
      alpha[r] = __expf(m_i[r] - mnew[r]);
      m_i[r] = mnew[r];
      float ssum = 0.f;
      #pragma unroll
      for (int ct = 0; ct < 4; ct++) { float e = __expf(sim[ct][r] - mnew[r]); p[ct][r] = e; ssum += e; }
      #pragma unroll
      for (int off = 8; off >= 1; off >>= 1) ssum += __shfl_xor(ssum, off, 16);
      l_i[r] = l_i[r] * alpha[r] + ssum;
    }
    #pragma unroll
    for (int ct = 0; ct < 4; ct++)
      #pragma unroll
      for (int r = 0; r < 4; r++)
        ps[wv][((lane>>4)*4 + r) * 88 + ct*16 + fr] = f2bf(p[ct][r]);
    #pragma unroll
    for (int dt = 0; dt < 4; dt++)
      #pragma unroll
      for (int r = 0; r < 4; r++) o[dt][r] *= alpha[r];
    short8 pa0 = *(const short8*)&ps[wv][fr * 88 + fq8];
    short8 pa1 = *(const short8*)&ps[wv][fr * 88 + 32 + fq8];
    #pragma unroll
    for (int dt = 0; dt < 4; dt++) {
      short8 bv0 = *(const short8*)&vs[(dt*16 + fr) * 88 + fq8];
      short8 bv1 = *(const short8*)&vs[(dt*16 + fr) * 88 + 32 + fq8];
      o[dt] = __builtin_amdgcn_mfma_f32_16x16x32_bf16(pa0, bv0, o[dt], 0, 0, 0);
      o[dt] = __builtin_amdgcn_mfma_f32_16x16x32_bf16(pa1, bv1, o[dt], 0, 0, 0);
    }
  }
  #pragma unroll
  for (int dt = 0; dt < 4; dt++)
    #pragma unroll
    for (int r = 0; r < 4; r++) {
      int row = wv * 16 + (lane>>4)*4 + r;
      int col = dt*16 + fr;
      opart[((size_t)id * 64 + row) * 64 + col] = o[dt][r];
    }
  if (fr == 0) {
    #pragma unroll
    for (int r = 0; r < 4; r++) {
      int row = wv * 16 + (lane>>4)*4 + r;
      mlpart[id * 128 + row * 2]     = m_i[r];
      mlpart[id * 128 + row * 2 + 1] = l_i[r];
    }
  }
}

// ---------------- combine the four key-parts ----------------
__global__ __launch_bounds__(256) void attn_comb_k(const float* __restrict__ opart,
    const float* __restrict__ mlpart, u16* __restrict__ out) {
  int bh = blockIdx.x;          // 128
  int b = bh >> 3, h = bh & 7;
  int tid = threadIdx.x;
  int row = tid >> 2;
  int c0 = (tid & 3) * 16;
  float mp[4], lp[4];
  float m = -1e30f;
  #pragma unroll
  for (int p = 0; p < 4; p++) {
    mp[p] = mlpart[(bh * 4 + p) * 128 + row * 2];
    lp[p] = mlpart[(bh * 4 + p) * 128 + row * 2 + 1];
    m = fmaxf(m, mp[p]);
  }
  float a[4]; float L = 0.f;
  #pragma unroll
  for (int p = 0; p < 4; p++) { a[p] = __expf(mp[p] - m); L += lp[p] * a[p]; }
  float rl = 1.f / L;
  u16* op = out + ((size_t)(b * LL + row)) * II + h * DHD + c0;
  #pragma unroll
  for (int j = 0; j < 4; j++) {
    float acc4[4] = {0.f, 0.f, 0.f, 0.f};
    #pragma unroll
    for (int p = 0; p < 4; p++) {
      const float4* pp = (const float4*)(opart + ((size_t)(bh * 4 + p) * 64 + row) * 64 + c0);
      float4 v = pp[j];
      acc4[0] += v.x * a[p]; acc4[1] += v.y * a[p];
      acc4[2] += v.z * a[p]; acc4[3] += v.w * a[p];
    }
    op[j*4 + 0] = f2bf(acc4[0] * rl);
    op[j*4 + 1] = f2bf(acc4[1] * rl);
    op[j*4 + 2] = f2bf(acc4[2] * rl);
    op[j*4 + 3] = f2bf(acc4[3] * rl);
  }
}

extern "C" void kernel_launch(void* const* d_in, const int* in_sizes, int n_in,
                              void* d_out, int out_size, void* d_ws, size_t ws_size,
                              hipStream_t stream) {
  (void)in_sizes; (void)n_in; (void)out_size; (void)ws_size;
  const float* x       = (const float*)d_in[0];
  const int*   mask    = (const int*)d_in[1];
  const float* latents = (const float*)d_in[2];
  const float* ln_m_w  = (const float*)d_in[3];
  const float* ln_m_b  = (const float*)d_in[4];
  const float* ln_l_w  = (const float*)d_in[5];
  const float* ln_l_b  = (const float*)d_in[6];
  const float* Wq      = (const float*)d_in[7];
  const float* Wkv     = (const float*)d_in[8];
  const float* Wo      = (const float*)d_in[9];
  const float* ff_ln_w = (const float*)d_in[10];
  const float* ff_ln_b = (const float*)d_in[11];
  const float* W1      = (const float*)d_in[12];
  const float* W2      = (const float*)d_in[13];
  const float* norm_w  = (const float*)d_in[14];
  const float* norm_b  = (const float*)d_in[15];
  float* out = (float*)d_out;

  char* ws = (char*)d_ws;
  size_t off = 0;
  auto alloc = [&](size_t bytes) -> void* {
    void* p = ws + off; off += (bytes + 255) & ~(size_t)255; return p;
  };
  u16* xcomp = (u16*)alloc((size_t)32768 * 1024 * 2);
  u16* kvk   = (u16*)alloc((size_t)32768 * 512 * 2);
  u16* vT    = (u16*)alloc((size_t)8192 * 2048 * 2);
  int* idxb  = (int*)alloc((size_t)32768 * 4);
  int* cnt   = (int*)alloc(64);
  float* lat = (float*)alloc((size_t)1024 * 1024 * 4);
  u16* lnl   = (u16*)alloc((size_t)1024 * 1024 * 2);
  u16* latn  = (u16*)alloc((size_t)1024 * 1024 * 2);
  u16* qkv   = (u16*)alloc((size_t)1024 * 1536 * 2);
  u16* aout  = (u16*)alloc((size_t)1024 * 512 * 2);
  u16* hf    = (u16*)alloc((size_t)1024 * 4096 * 2);
  float* opart  = (float*)alloc((size_t)512 * 64 * 64 * 4);
  float* mlpart = (float*)alloc((size_t)512 * 128 * 4);
  u16* WqkvT = (u16*)alloc((size_t)DEPTHC * 1536 * 1024 * 2);
  u16* WkvTf = (u16*)alloc((size_t)DEPTHC * 1024 * 1024 * 2);
  u16* WoT   = (u16*)alloc((size_t)DEPTHC * 1024 * 512 * 2);
  u16* W1T   = (u16*)alloc((size_t)DEPTHC * 4096 * 1024 * 2);
  u16* W2T   = (u16*)alloc((size_t)DEPTHC * 1024 * 4096 * 2);
  float* biaskv_all = (float*)alloc(DEPTHC * 1024 * 4);

  // pre-loop: compaction + bias zero, then W1/W2 transposes, then fused qkvo+LN-gather+lat-init
  maskscan_k<<<16, 256, 0, stream>>>(mask, idxb, cnt);
  zero_k<<<24, 256, 0, stream>>>(biaskv_all, DEPTHC * 1024);
  transp_w_k<<<DEPTHC * 1024, 256, 0, stream>>>(W1, W1T, 1024, 4096, 6);
  transp_w_k<<<DEPTHC * 1024, 256, 0, stream>>>(W2, W2T, 4096, 1024, 4);
  qkvo_fused_k<<<3072 + 32768 + 1024, 256, 0, stream>>>(
      Wq, Wkv, Wo, ln_m_w, ln_m_b,
      WqkvT, WoT, WkvTf, biaskv_all,
      x, idxb, cnt, xcomp, latents, lat);

  for (int i = 0; i < DEPTHC; i++) {
    ln_rows_k<false><<<1024, 256, 0, stream>>>(lat, ln_l_w + i*1024, ln_l_b + i*1024, lnl);
    gemm_fused_k<<<2144, 256, 0, stream>>>(
        xcomp, WkvTf + (size_t)i*1024*1024, kvk, vT, biaskv_all + i*1024, cnt,
        lnl, WqkvT + (size_t)i*1536*1024, qkv);
    attn_part_k<<<512, 256, 0, stream>>>(qkv, kvk, vT, cnt, opart, mlpart);
    attn_comb_k<<<128, 256, 0, stream>>>(opart, mlpart, aout);
    gemmsk_k<<<dim3(16, 8, 4), 256, 0, stream>>>(aout, WoT + (size_t)i*1024*512, lat, 1024, 1024, 512, 128);
    ln_rows_k<false><<<1024, 256, 0, stream>>>(lat, ff_ln_w + i*1024, ff_ln_b + i*1024, latn);
    gemm_gelu_k<<<dim3(64, 8), 256, 0, stream>>>(latn, W1T + (size_t)i*4096*1024, hf, 1024, 4096, 1024);
    gemmsk_k<<<dim3(16, 8, 4), 256, 0, stream>>>(hf, W2T + (size_t)i*1024*4096, lat, 1024, 1024, 4096, 1024);
  }
  ln_rows_k<true><<<1024, 256, 0, stream>>>(lat, norm_w, norm_b, out);
}

// Round 11
// 1388.382 us; speedup vs baseline: 1.2029x; 1.0367x over previous
//
#include <hip/hip_runtime.h>

typedef unsigned short u16;
typedef unsigned int u32;
typedef __attribute__((ext_vector_type(8))) short short8;
typedef __attribute__((ext_vector_type(4))) float f4;

#define DEV static __device__ __forceinline__

constexpr int BB = 16, NN = 2048, DD = 1024, HH = 8, DHD = 64, II = 512, LL = 64, DEPTHC = 6, FFC = 4096;

DEV u16 f2bf(float f) {
  union { float f; u32 u; } v; v.f = f;
  u32 r = v.u + 0x7FFFu + ((v.u >> 16) & 1u);
  return (u16)(r >> 16);
}

DEV u32 pack2(float lo, float hi) {
  return (u32)f2bf(lo) | ((u32)f2bf(hi) << 16);
}

typedef const u32 __attribute__((address_space(1)))* gas_p;
typedef u32 __attribute__((address_space(3)))* las_p;
DEV void gl_lds16(const void* g, void* l) {
  __builtin_amdgcn_global_load_lds((gas_p)g, (las_p)l, 16, 0, 0);
}

// ---------------- mask prefix-scan: per batch, list of unmasked (mask==0) indices ----------------
__global__ __launch_bounds__(256) void maskscan_k(const int* __restrict__ mask,
    int* __restrict__ idx, int* __restrict__ cnt) {
  int b = blockIdx.x, tid = threadIdx.x;
  int lane = tid & 63, wv = tid >> 6;
  const int* mrow = mask + (size_t)b * NN;
  int base = tid * 8;
  int keep[8]; int local = 0;
  #pragma unroll
  for (int j = 0; j < 8; j++) { keep[j] = (mrow[base + j] == 0); local += keep[j]; }
  int incl = local;
  #pragma unroll
  for (int off = 1; off < 64; off <<= 1) {
    int v = __shfl_up(incl, off, 64);
    if (lane >= off) incl += v;
  }
  __shared__ int wsum[4];
  if (lane == 63) wsum[wv] = incl;
  __syncthreads();
  int wbase = 0;
  for (int w = 0; w < wv; w++) wbase += wsum[w];
  int pos = wbase + incl - local;
  #pragma unroll
  for (int j = 0; j < 8; j++) if (keep[j]) idx[(size_t)b * NN + pos++] = base + j;
  if (tid == 255) cnt[b] = wbase + incl;
}

// ---------------- zero small buffer ----------------
__global__ void zero_k(float* __restrict__ p, int n) {
  int i = blockIdx.x * 256 + threadIdx.x;
  if (i < n) p[i] = 0.f;
}

// ---------------- W1 / W2 transpose: 64x64 tiles, 1024 tiles per depth ----------------
__global__ __launch_bounds__(256) void transp_w_k(const float* __restrict__ Wa, u16* __restrict__ WTa,
    int R, int C, int ctLog) {
  __shared__ float t[64][65];
  int gid = blockIdx.x;
  int depth = gid >> 10;
  int l = gid & 1023;
  int c0 = (l & ((1 << ctLog) - 1)) << 6;
  int r0 = (l >> ctLog) << 6;
  const float* in = Wa + (size_t)depth * 4096 * 1024;
  u16* o1 = WTa + (size_t)depth * 4096 * 1024;
  int tid = threadIdx.x;
  int lr = tid >> 4, lc4 = (tid & 15) * 4;
  #pragma unroll
  for (int p = 0; p < 4; p++) {
    int row = p * 16 + lr;
    float4 v = *(const float4*)&in[(size_t)(r0 + row) * C + c0 + lc4];
    t[row][lc4] = v.x; t[row][lc4+1] = v.y; t[row][lc4+2] = v.z; t[row][lc4+3] = v.w;
  }
  __syncthreads();
  int oc = tid >> 3;
  int rg = tid & 7;
  #pragma unroll
  for (int p = 0; p < 2; p++) {
    int c = p * 32 + oc;
    float v[8];
    #pragma unroll
    for (int k = 0; k < 8; k++) v[k] = t[rg * 8 + k][c];
    int4 o;
    o.x = (int)pack2(v[0], v[1]); o.y = (int)pack2(v[2], v[3]);
    o.z = (int)pack2(v[4], v[5]); o.w = (int)pack2(v[6], v[7]);
    *(int4*)&o1[(size_t)(c0 + c) * R + r0 + rg * 8] = o;
  }
}

// ---------------- fused pre-pass: Wq/Wkv/Wo transposes (+kv fold) | LN-gather | lat-init ----------
__global__ __launch_bounds__(256) void qkvo_fused_k(
    const float* __restrict__ WqA, const float* __restrict__ WkvA, const float* __restrict__ WoA,
    const float* __restrict__ lnwA, const float* __restrict__ lnbA,
    u16* __restrict__ WqkvTA, u16* __restrict__ WoTA, u16* __restrict__ WkvTfA,
    float* __restrict__ biaskvA,
    const float* __restrict__ x, const int* __restrict__ idx, const int* __restrict__ cnt,
    u16* __restrict__ xcomp, const float* __restrict__ latents, float* __restrict__ lat) {
  __shared__ float t[64][65];
  __shared__ float red8[8];
  int gid = blockIdx.x;
  int tid = threadIdx.x;
  if (gid < 3072) {
    int depth = gid >> 9;
    int id = gid & 511;
    const float* in; u16* o1; int R, C, c0, r0;
    bool iskv = false;
    if (id < 128)      { in = WqA  + (size_t)depth*1024*512;  R = 1024; C = 512;  int l = id;       c0 = (l & 7) * 64;  r0 = (l >> 3) * 64; o1 = WqkvTA + (size_t)depth*1536*1024; }
    else if (id < 384) { in = WkvA + (size_t)depth*1024*1024; R = 1024; C = 1024; int l = id - 128; c0 = (l & 15) * 64; r0 = (l >> 4) * 64; o1 = WqkvTA + (size_t)depth*1536*1024 + 512*1024; iskv = true; }
    else               { in = WoA  + (size_t)depth*512*1024;  R = 512;  C = 1024; int l = id - 384; c0 = (l & 15) * 64; r0 = (l >> 4) * 64; o1 = WoTA + (size_t)depth*1024*512; }
    int lr = tid >> 4, lc4 = (tid & 15) * 4;
    #pragma unroll
    for (int p = 0; p < 4; p++) {
      int row = p * 16 + lr;
      float4 v = *(const float4*)&in[(size_t)(r0 + row) * C + c0 + lc4];
      t[row][lc4] = v.x; t[row][lc4+1] = v.y; t[row][lc4+2] = v.z; t[row][lc4+3] = v.w;
    }
    int oc = tid >> 3;
    int rg = tid & 7;
    float lw[8], lb[8];
    if (iskv) {
      const float* lnw = lnwA + depth * 1024;
      const float* lnb = lnbA + depth * 1024;
      int rbase = r0 + rg * 8;
      float4 w0 = *(const float4*)&lnw[rbase];
      float4 w1 = *(const float4*)&lnw[rbase + 4];
      float4 b0 = *(const float4*)&lnb[rbase];
      float4 b1 = *(const float4*)&lnb[rbase + 4];
      lw[0]=w0.x; lw[1]=w0.y; lw[2]=w0.z; lw[3]=w0.w; lw[4]=w1.x; lw[5]=w1.y; lw[6]=w1.z; lw[7]=w1.w;
      lb[0]=b0.x; lb[1]=b0.y; lb[2]=b0.z; lb[3]=b0.w; lb[4]=b1.x; lb[5]=b1.y; lb[6]=b1.z; lb[7]=b1.w;
    }
    __syncthreads();
    #pragma unroll
    for (int p = 0; p < 2; p++) {
      int c = p * 32 + oc;
      float v[8];
      #pragma unroll
      for (int k = 0; k < 8; k++) v[k] = t[rg * 8 + k][c];
      int4 o;
      o.x = (int)pack2(v[0], v[1]); o.y = (int)pack2(v[2], v[3]);
      o.z = (int)pack2(v[4], v[5]); o.w = (int)pack2(v[6], v[7]);
      *(int4*)&o1[(size_t)(c0 + c) * R + r0 + rg * 8] = o;
      if (iskv) {
        u16* WkvTf = WkvTfA + (size_t)depth*1024*1024;
        int4 of;
        of.x = (int)pack2(v[0]*lw[0], v[1]*lw[1]); of.y = (int)pack2(v[2]*lw[2], v[3]*lw[3]);
        of.z = (int)pack2(v[4]*lw[4], v[5]*lw[5]); of.w = (int)pack2(v[6]*lw[6], v[7]*lw[7]);
        *(int4*)&WkvTf[(size_t)(c0 + c) * 1024 + r0 + rg * 8] = of;
        float partial = 0.f;
        #pragma unroll
        for (int k = 0; k < 8; k++) partial += lb[k] * v[k];
        partial += __shfl_xor(partial, 1, 64);
        partial += __shfl_xor(partial, 2, 64);
        partial += __shfl_xor(partial, 4, 64);
        if (rg == 0) atomicAdd(&biaskvA[depth*1024 + c0 + c], partial);
      }
    }
    return;
  }
  gid -= 3072;
  if (gid < 32768) {
    // ---- ln_gather (zero-pad to 256-row alignment) ----
    int b = gid >> 11, j = gid & 2047;
    int c = cnt[b];
    if (j >= ((c + 255) & ~255)) return;
    ushort4* orow = (ushort4*)(xcomp + ((size_t)b * NN + j) * DD);
    if (j >= c) { orow[tid] = make_ushort4(0, 0, 0, 0); return; }
    int src = idx[(size_t)b * NN + j];
    const float4* rp = (const float4*)(x + ((size_t)b * NN + src) * DD);
    float4 v = rp[tid];
    float s = v.x + v.y + v.z + v.w;
    float s2 = v.x*v.x + v.y*v.y + v.z*v.z + v.w*v.w;
    #pragma unroll
    for (int off = 32; off >= 1; off >>= 1) {
      s  += __shfl_xor(s, off, 64);
      s2 += __shfl_xor(s2, off, 64);
    }
    int wv = tid >> 6;
    if ((tid & 63) == 0) { red8[wv] = s; red8[4 + wv] = s2; }
    __syncthreads();
    s  = red8[0] + red8[1] + red8[2] + red8[3];
    s2 = red8[4] + red8[5] + red8[6] + red8[7];
    float mu = s * (1.f / DD);
    float var = s2 * (1.f / DD) - mu * mu;
    float rstd = rsqrtf(var + 1e-5f);
    orow[tid] = make_ushort4(f2bf((v.x - mu) * rstd), f2bf((v.y - mu) * rstd),
                             f2bf((v.z - mu) * rstd), f2bf((v.w - mu) * rstd));
    return;
  }
  gid -= 32768;
  // ---- lat_init ----
  int i2 = gid * 256 + tid;
  ((float4*)lat)[i2] = ((const float4*)latents)[i2 & (LL * DD / 4 - 1)];
}

// ---------------- LayerNorm over rows of 1024 (latent path) ----------------
template<bool OUTF32>
__global__ __launch_bounds__(256) void ln_rows_k(const float* __restrict__ in,
    const float* __restrict__ w, const float* __restrict__ bias, void* __restrict__ out) {
  int row = blockIdx.x;
  int tid = threadIdx.x;
  const float4* rp = (const float4*)(in + (size_t)row * DD);
  float4 x = rp[tid];
  float s = x.x + x.y + x.z + x.w;
  float s2 = x.x*x.x + x.y*x.y + x.z*x.z + x.w*x.w;
  #pragma unroll
  for (int off = 32; off >= 1; off >>= 1) {
    s  += __shfl_xor(s, off, 64);
    s2 += __shfl_xor(s2, off, 64);
  }
  __shared__ float red[8];
  int wv = tid >> 6;
  if ((tid & 63) == 0) { red[wv] = s; red[4 + wv] = s2; }
  __syncthreads();
  s  = red[0] + red[1] + red[2] + red[3];
  s2 = red[4] + red[5] + red[6] + red[7];
  float mu = s * (1.f / DD);
  float var = s2 * (1.f / DD) - mu * mu;
  float rstd = rsqrtf(var + 1e-5f);
  float y[4] = {x.x, x.y, x.z, x.w};
  int col = tid * 4;
  #pragma unroll
  for (int j = 0; j < 4; j++)
    y[j] = (y[j] - mu) * rstd * w[col + j] + bias[col + j];
  if (OUTF32) {
    float4 o = {y[0], y[1], y[2], y[3]};
    ((float4*)out)[(size_t)row * (DD/4) + tid] = o;
  } else {
    ushort4 o = make_ushort4(f2bf(y[0]), f2bf(y[1]), f2bf(y[2]), f2bf(y[3]));
    ((ushort4*)out)[(size_t)row * (DD/4) + tid] = o;
  }
}

// ---------------- fused GEMM launch: kv (2048 swizzled blocks) + latent qkv (96 blocks) ----------
// 128x128 tile, BK=32, chunk-XOR swizzle + DOUBLE-BUFFERED LDS (stage k+1 overlaps compute k,
// one barrier per K-step; __syncthreads supplies the vmcnt/lgkm drain).
__global__ __launch_bounds__(256) void gemm_fused_k(
    const u16* __restrict__ xcomp, const u16* __restrict__ WkvTf,
    u16* __restrict__ kvk, u16* __restrict__ vT,
    const float* __restrict__ bias, const int* __restrict__ cnt,
    const u16* __restrict__ lnl, const u16* __restrict__ WqkvT, u16* __restrict__ qkv) {
  __shared__ __align__(16) u16 As[2 * 128 * 32];
  __shared__ __align__(16) u16 Bs[2 * 128 * 32];
  int id = blockIdx.x;
  int tid = threadIdx.x;
  int wv = tid >> 6, lane = tid & 63;
  const u16 *A, *B;
  int m0, n0, batch = 0, ml = 0;
  bool iskv;
  if (id < 2048) {
    int xg = id & 7, t = id >> 3;
    int mtile = xg * 32 + (t >> 3);
    n0 = (t & 7) * 128;
    batch = mtile >> 4;
    ml = (mtile & 15) * 128;
    if (ml >= cnt[batch]) return;
    m0 = batch * NN + ml;
    A = xcomp; B = WkvTf; iskv = true;
  } else {
    int l = id - 2048;            // 8 mtiles x 12 ntiles
    m0 = (l / 12) * 128; n0 = (l % 12) * 128;
    A = lnl; B = WqkvT; iskv = false;
  }
  const int K = 1024;
  int srow = wv * 16 + (lane >> 2);
  int sg = (((lane & 3) ^ ((lane >> 3) & 3))) * 8;  // swizzled global chunk offset
  int sl = (lane & 3) * 8;                           // linear LDS chunk offset
  const u16* gA0 = A + (size_t)(m0 + srow) * K + sg;
  const u16* gA1 = A + (size_t)(m0 + 64 + srow) * K + sg;
  const u16* gB0 = B + (size_t)(n0 + srow) * K + sg;
  const u16* gB1 = B + (size_t)(n0 + 64 + srow) * K + sg;
  int wA0 = srow * 32 + sl, wA1 = (64 + srow) * 32 + sl;
  int wm = (wv & 1) * 64, wn = (wv >> 1) * 64;
  int fr = lane & 15;
  int cs = (((lane >> 4) ^ ((lane >> 1) & 3))) * 8;  // swizzled read chunk offset
  f4 acc[4][4];
  #pragma unroll
  for (int mi = 0; mi < 4; mi++)
    #pragma unroll
    for (int ni = 0; ni < 4; ni++) acc[mi][ni] = f4{0.f, 0.f, 0.f, 0.f};

  // prologue: stage tile 0 into buffer 0
  gl_lds16(gA0, &As[wA0]);
  gl_lds16(gA1, &As[wA1]);
  gl_lds16(gB0, &Bs[wA0]);
  gl_lds16(gB1, &Bs[wA1]);
  __syncthreads();
  int cur = 0;
  for (int k0 = 32; k0 < K; k0 += 32) {
    int nb = (cur ^ 1) * 4096;
    gl_lds16(gA0 + k0, &As[nb + wA0]);
    gl_lds16(gA1 + k0, &As[nb + wA1]);
    gl_lds16(gB0 + k0, &Bs[nb + wA0]);
    gl_lds16(gB1 + k0, &Bs[nb + wA1]);
    int cb = cur * 4096;
    short8 af[4], bfr[4];
    #pragma unroll
    for (int mi = 0; mi < 4; mi++)
      af[mi] = *(const short8*)&As[cb + (wm + mi*16 + fr) * 32 + cs];
    #pragma unroll
    for (int ni = 0; ni < 4; ni++)
      bfr[ni] = *(const short8*)&Bs[cb + (wn + ni*16 + fr) * 32 + cs];
    #pragma unroll
    for (int mi = 0; mi < 4; mi++)
      #pragma unroll
      for (int ni = 0; ni < 4; ni++)
        acc[mi][ni] = __builtin_amdgcn_mfma_f32_16x16x32_bf16(af[mi], bfr[ni], acc[mi][ni], 0, 0, 0);
    __syncthreads();   // drains next-tile loads (they flew during compute) + lgkm
    cur ^= 1;
  }
  {
    int cb = cur * 4096;
    short8 af[4], bfr[4];
    #pragma unroll
    for (int mi = 0; mi < 4; mi++)
      af[mi] = *(const short8*)&As[cb + (wm + mi*16 + fr) * 32 + cs];
    #pragma unroll
    for (int ni = 0; ni < 4; ni++)
      bfr[ni] = *(const short8*)&Bs[cb + (wn + ni*16 + fr) * 32 + cs];
    #pragma unroll
    for (int mi = 0; mi < 4; mi++)
      #pragma unroll
      for (int ni = 0; ni < 4; ni++)
        acc[mi][ni] = __builtin_amdgcn_mfma_f32_16x16x32_bf16(af[mi], bfr[ni], acc[mi][ni], 0, 0, 0);
  }
  int er = (lane >> 4) * 4;
  int ec = lane & 15;
  if (iskv) {
    #pragma unroll
    for (int mi = 0; mi < 4; mi++) {
      int rbase = wm + mi*16 + er;
      #pragma unroll
      for (int ni = 0; ni < 4; ni++) {
        int col = n0 + wn + ni*16 + ec;
        float bv = bias[col];
        if (col < 512) {
          #pragma unroll
          for (int r = 0; r < 4; r++)
            kvk[(size_t)(m0 + rbase + r) * 512 + col] = f2bf(acc[mi][ni][r] + bv);
        } else {
          int d = col - 512;
          int hh = d >> 6, dl = d & 63;
          ushort4 o4;
          o4.x = f2bf(acc[mi][ni][0] + bv);
          o4.y = f2bf(acc[mi][ni][1] + bv);
          o4.z = f2bf(acc[mi][ni][2] + bv);
          o4.w = f2bf(acc[mi][ni][3] + bv);
          *(ushort4*)(vT + ((size_t)((batch * 8 + hh) * 64 + dl)) * NN + (ml + rbase)) = o4;
        }
      }
    }
  } else {
    #pragma unroll
    for (int mi = 0; mi < 4; mi++)
      #pragma unroll
      for (int ni = 0; ni < 4; ni++) {
        int col = n0 + wn + ni*16 + ec;
        #pragma unroll
        for (int r = 0; r < 4; r++) {
          int row = m0 + wm + mi*16 + er + r;
          qkv[(size_t)row * 1536 + col] = f2bf(acc[mi][ni][r]);
        }
      }
  }
}

// ---------------- GEMM 128x64 gelu epilogue (W1), chunk-swizzled + double-buffered ----------
__global__ __launch_bounds__(256) void gemm_gelu_k(const u16* __restrict__ A, const u16* __restrict__ Bm,
    u16* __restrict__ C, int M, int N, int K) {
  __shared__ __align__(16) u16 As[2 * 128 * 32];
  __shared__ __align__(16) u16 Bs[2 * 64 * 32];
  int tid = threadIdx.x;
  int wv = tid >> 6, lane = tid & 63;
  int m0 = blockIdx.y * 128, n0 = blockIdx.x * 64;
  int srow = wv * 16 + (lane >> 2);
  int sg = (((lane & 3) ^ ((lane >> 3) & 3))) * 8;
  int sl = (lane & 3) * 8;
  const u16* gA0 = A + (size_t)(m0 + srow) * K + sg;
  const u16* gA1 = A + (size_t)(m0 + 64 + srow) * K + sg;
  const u16* gB0 = Bm + (size_t)(n0 + srow) * K + sg;
  int wA0 = srow * 32 + sl, wA1 = (64 + srow) * 32 + sl;
  int wm = (wv & 1) * 64, wn = (wv >> 1) * 32;
  int fr = lane & 15;
  int cs = (((lane >> 4) ^ ((lane >> 1) & 3))) * 8;
  f4 acc[4][2];
  #pragma unroll
  for (int mi = 0; mi < 4; mi++)
    #pragma unroll
    for (int ni = 0; ni < 2; ni++) acc[mi][ni] = f4{0.f, 0.f, 0.f, 0.f};

  gl_lds16(gA0, &As[wA0]);
  gl_lds16(gA1, &As[wA1]);
  gl_lds16(gB0, &Bs[wA0]);
  __syncthreads();
  int cur = 0;
  for (int k0 = 32; k0 < K; k0 += 32) {
    gl_lds16(gA0 + k0, &As[(cur ^ 1) * 4096 + wA0]);
    gl_lds16(gA1 + k0, &As[(cur ^ 1) * 4096 + wA1]);
    gl_lds16(gB0 + k0, &Bs[(cur ^ 1) * 2048 + wA0]);
    short8 af[4], bfr[2];
    #pragma unroll
    for (int mi = 0; mi < 4; mi++)
      af[mi] = *(const short8*)&As[cur * 4096 + (wm + mi*16 + fr) * 32 + cs];
    #pragma unroll
    for (int ni = 0; ni < 2; ni++)
      bfr[ni] = *(const short8*)&Bs[cur * 2048 + (wn + ni*16 + fr) * 32 + cs];
    #pragma unroll
    for (int mi = 0; mi < 4; mi++)
      #pragma unroll
      for (int ni = 0; ni < 2; ni++)
        acc[mi][ni] = __builtin_amdgcn_mfma_f32_16x16x32_bf16(af[mi], bfr[ni], acc[mi][ni], 0, 0, 0);
    __syncthreads();
    cur ^= 1;
  }
  {
    short8 af[4], bfr[2];
    #pragma unroll
    for (int mi = 0; mi < 4; mi++)
      af[mi] = *(const short8*)&As[cur * 4096 + (wm + mi*16 + fr) * 32 + cs];
    #pragma unroll
    for (int ni = 0; ni < 2; ni++)
      bfr[ni] = *(const short8*)&Bs[cur * 2048 + (wn + ni*16 + fr) * 32 + cs];
    #pragma unroll
    for (int mi = 0; mi < 4; mi++)
      #pragma unroll
      for (int ni = 0; ni < 2; ni++)
        acc[mi][ni] = __builtin_amdgcn_mfma_f32_16x16x32_bf16(af[mi], bfr[ni], acc[mi][ni], 0, 0, 0);
  }
  int er = (lane >> 4) * 4;
  int ec = lane & 15;
  #pragma unroll
  for (int mi = 0; mi < 4; mi++)
    #pragma unroll
    for (int ni = 0; ni < 2; ni++) {
      int col = n0 + wn + ni*16 + ec;
      #pragma unroll
      for (int r = 0; r < 4; r++) {
        int row = m0 + wm + mi*16 + er + r;
        float v = acc[mi][ni][r];
        v = 0.5f * v * (1.f + erff(v * 0.70710678118654752f));
        C[(size_t)row * N + col] = f2bf(v);
      }
    }
}

// ---------------- split-K GEMM 128x64, fp32 atomicAdd epilogue, swizzled + double-buffered ------
__global__ __launch_bounds__(256) void gemmsk_k(const u16* __restrict__ A, const u16* __restrict__ Bm,
    float* __restrict__ C, int M, int N, int K, int Kc) {
  __shared__ __align__(16) u16 As[2 * 128 * 32];
  __shared__ __align__(16) u16 Bs[2 * 64 * 32];
  int tid = threadIdx.x;
  int wv = tid >> 6, lane = tid & 63;
  int m0 = blockIdx.y * 128, n0 = blockIdx.x * 64;
  int kb = blockIdx.z * Kc;
  int srow = wv * 16 + (lane >> 2);
  int sg = (((lane & 3) ^ ((lane >> 3) & 3))) * 8;
  int sl = (lane & 3) * 8;
  const u16* gA0 = A + (size_t)(m0 + srow) * K + kb + sg;
  const u16* gA1 = A + (size_t)(m0 + 64 + srow) * K + kb + sg;
  const u16* gB0 = Bm + (size_t)(n0 + srow) * K + kb + sg;
  int wA0 = srow * 32 + sl, wA1 = (64 + srow) * 32 + sl;
  int wm = (wv & 1) * 64, wn = (wv >> 1) * 32;
  int fr = lane & 15;
  int cs = (((lane >> 4) ^ ((lane >> 1) & 3))) * 8;
  f4 acc[4][2];
  #pragma unroll
  for (int mi = 0; mi < 4; mi++)
    #pragma unroll
    for (int ni = 0; ni < 2; ni++) acc[mi][ni] = f4{0.f, 0.f, 0.f, 0.f};

  gl_lds16(gA0, &As[wA0]);
  gl_lds16(gA1, &As[wA1]);
  gl_lds16(gB0, &Bs[wA0]);
  __syncthreads();
  int cur = 0;
  for (int k0 = 32; k0 < Kc; k0 += 32) {
    gl_lds16(gA0 + k0, &As[(cur ^ 1) * 4096 + wA0]);
    gl_lds16(gA1 + k0, &As[(cur ^ 1) * 4096 + wA1]);
    gl_lds16(gB0 + k0, &Bs[(cur ^ 1) * 2048 + wA0]);
    short8 af[4], bfr[2];
    #pragma unroll
    for (int mi = 0; mi < 4; mi++)
      af[mi] = *(const short8*)&As[cur * 4096 + (wm + mi*16 + fr) * 32 + cs];
    #pragma unroll
    for (int ni = 0; ni < 2; ni++)
      bfr[ni] = *(const short8*)&Bs[cur * 2048 + (wn + ni*16 + fr) * 32 + cs];
    #pragma unroll
    for (int mi = 0; mi < 4; mi++)
      #pragma unroll
      for (int ni = 0; ni < 2; ni++)
        acc[mi][ni] = __builtin_amdgcn_mfma_f32_16x16x32_bf16(af[mi], bfr[ni], acc[mi][ni], 0, 0, 0);
    __syncthreads();
    cur ^= 1;
  }
  {
    short8 af[4], bfr[2];
    #pragma unroll
    for (int mi = 0; mi < 4; mi++)
      af[mi] = *(const short8*)&As[cur * 4096 + (wm + mi*16 + fr) * 32 + cs];
    #pragma unroll
    for (int ni = 0; ni < 2; ni++)
      bfr[ni] = *(const short8*)&Bs[cur * 2048 + (wn + ni*16 + fr) * 32 + cs];
    #pragma unroll
    for (int mi = 0; mi < 4; mi++)
      #pragma unroll
      for (int ni = 0; ni < 2; ni++)
        acc[mi][ni] = __builtin_amdgcn_mfma_f32_16x16x32_bf16(af[mi], bfr[ni], acc[mi][ni], 0, 0, 0);
  }
  int er = (lane >> 4) * 4;
  int ec = lane & 15;
  #pragma unroll
  for (int mi = 0; mi < 4; mi++)
    #pragma unroll
    for (int ni = 0; ni < 2; ni++) {
      int col = n0 + wn + ni*16 + ec;
      #pragma unroll
      for (int r = 0; r < 4; r++) {
        int row = m0 + wm + mi*16 + er + r;
        atomicAdd(&C[(size_t)row * N + col], acc[mi][ni][r]);
      }
    }
}

// ---------------- flash attention, split over keys: 4 blocks per (b,h) ----------------
__global__ __launch_bounds__(256) void attn_part_k(const u16* __restrict__ qkv,
    const u16* __restrict__ kvk, const u16* __restrict__ vT, const int* __restrict__ cnt,
    float* __restrict__ opart, float* __restrict__ mlpart) {
  int id = blockIdx.x;          // 512
  int b = id >> 5;
  int h = (id >> 2) & 7;
  int part = id & 3;
  int tid = threadIdx.x;
  int wv = tid >> 6, lane = tid & 63;
  int fr = lane & 15, fq8 = (lane >> 4) * 8;
  int c = cnt[b];
  int nt = (c + 63) >> 6;
  int T = nt + 1;
  int t0 = (T * part) >> 2;
  int t1 = (T * (part + 1)) >> 2;

  __shared__ __align__(16) u16 ks[64 * 88];
  __shared__ __align__(16) u16 vs[64 * 88];
  __shared__ __align__(16) u16 ps[4][16 * 88];
  __shared__ float smask[64];

  const u16* qp = qkv + (size_t)(b * LL + wv * 16 + fr) * 1536 + h * DHD;
  short8 aq0 = *(const short8*)(qp + fq8);
  short8 aq1 = *(const short8*)(qp + 32 + fq8);

  float m_i[4], l_i[4];
  f4 o[4];
  #pragma unroll
  for (int r = 0; r < 4; r++) { m_i[r] = -1e30f; l_i[r] = 0.f; }
  #pragma unroll
  for (int dt = 0; dt < 4; dt++) o[dt] = f4{0.f, 0.f, 0.f, 0.f};

  const float scale = 0.125f;

  for (int t = t0; t < t1; t++) {
    bool isLat = (t == nt);
    __syncthreads();
    if (isLat) {
      const u16* src = qkv + (size_t)(b * LL) * 1536 + 512 + h * DHD;
      #pragma unroll
      for (int it = 0; it < 2; it++) {
        int cid = it * 256 + tid;
        int kr = cid >> 3, c8 = (cid & 7) * 8;
        int4 kvv = *(const int4*)(src + (size_t)kr * 1536 + c8);
        *(int4*)&ks[kr * 88 + c8] = kvv;
        int4 vvv = *(const int4*)(src + 512 + (size_t)kr * 1536 + c8);
        const u16* ve = (const u16*)&vvv;
        #pragma unroll
        for (int j = 0; j < 8; j++) vs[(c8 + j) * 88 + kr] = ve[j];
      }
    } else {
      const u16* ksrc = kvk + (size_t)(b * NN + t * 64) * 512 + h * DHD;
      const u16* vsrc = vT + (size_t)((b * 8 + h) * 64) * NN + t * 64;
      #pragma unroll
      for (int it = 0; it < 2; it++) {
        int cid = it * 256 + tid;
        int kr = cid >> 3, c8 = (cid & 7) * 8;
        *(int4*)&ks[kr * 88 + c8] = *(const int4*)(ksrc + (size_t)kr * 512 + c8);
        *(int4*)&vs[kr * 88 + c8] = *(const int4*)(vsrc + (size_t)kr * NN + c8);
      }
    }
    if (tid < 64)
      smask[tid] = (isLat || (t * 64 + tid < c)) ? 0.f : -1e30f;
    __syncthreads();

    f4 sim[4];
    #pragma unroll
    for (int ct = 0; ct < 4; ct++) {
      short8 b0 = *(const short8*)&ks[(ct*16 + fr) * 88 + fq8];
      short8 b1 = *(const short8*)&ks[(ct*16 + fr) * 88 + 32 + fq8];
      f4 s = f4{0.f, 0.f, 0.f, 0.f};
      s = __builtin_amdgcn_mfma_f32_16x16x32_bf16(aq0, b0, s, 0, 0, 0);
      s = __builtin_amdgcn_mfma_f32_16x16x32_bf16(aq1, b1, s, 0, 0, 0);
      float mk = smask[ct*16 + fr];
      #pragma unroll
      for (int r = 0; r < 4; r++) s[r] = s[r] * scale + mk;
      sim[ct] = s;
    }
    float mnew[4], alpha[4], p[4][4];
    #pragma unroll
    for (int r = 0; r < 4; r++) {
      float mx = fmaxf(fmaxf(sim[0][r], sim[1][r]), fmaxf(sim[2][r], sim[3][r]));
      #pragma unroll
      for (int off = 8; off >= 1; off >>= 1) mx = fmaxf(mx, __shfl_xor(mx, off, 16));
      mnew[r] = fmaxf(m_i[r], mx);
      alpha[r] = __expf(m_i[r] - mnew[r]);
      m_i[r] = mnew[r];
      float ssum = 0.f;
      #pragma unroll
      for (int ct = 0; ct < 4; ct++) { float e = __expf(sim[ct][r] - mnew[r]); p[ct][r] = e; ssum += e; }
      #pragma unroll
      for (int off = 8; off >= 1; off >>= 1) ssum += __shfl_xor(ssum, off, 16);
      l_i[r] = l_i[r] * alpha[r] + ssum;
    }
    #pragma unroll
    for (int ct = 0; ct < 4; ct++)
      #pragma unroll
      for (int r = 0; r < 4; r++)
        ps[wv][((lane>>4)*4 + r) * 88 + ct*16 + fr] = f2bf(p[ct][r]);
    #pragma unroll
    for (int dt = 0; dt < 4; dt++)
      #pragma unroll
      for (int r = 0; r < 4; r++) o[dt][r] *= alpha[r];
    short8 pa0 = *(const short8*)&ps[wv][fr * 88 + fq8];
    short8 pa1 = *(const short8*)&ps[wv][fr * 88 + 32 + fq8];
    #pragma unroll
    for (int dt = 0; dt < 4; dt++) {
      short8 bv0 = *(const short8*)&vs[(dt*16 + fr) * 88 + fq8];
      short8 bv1 = *(const short8*)&vs[(dt*16 + fr) * 88 + 32 + fq8];
      o[dt] = __builtin_amdgcn_mfma_f32_16x16x32_bf16(pa0, bv0, o[dt], 0, 0, 0);
      o[dt] = __builtin_amdgcn_mfma_f32_16x16x32_bf16(pa1, bv1, o[dt], 0, 0, 0);
    }
  }
  #pragma unroll
  for (int dt = 0; dt < 4; dt++)
    #pragma unroll
    for (int r = 0; r < 4; r++) {
      int row = wv * 16 + (lane>>4)*4 + r;
      int col = dt*16 + fr;
      opart[((size_t)id * 64 + row) * 64 + col] = o[dt][r];
    }
  if (fr == 0) {
    #pragma unroll
    for (int r = 0; r < 4; r++) {
      int row = wv * 16 + (lane>>4)*4 + r;
      mlpart[id * 128 + row * 2]     = m_i[r];
      mlpart[id * 128 + row * 2 + 1] = l_i[r];
    }
  }
}

// ---------------- combine the four key-parts ----------------
__global__ __launch_bounds__(256) void attn_comb_k(const float* __restrict__ opart,
    const float* __restrict__ mlpart, u16* __restrict__ out) {
  int bh = blockIdx.x;          // 128
  int b = bh >> 3, h = bh & 7;
  int tid = threadIdx.x;
  int row = tid >> 2;
  int c0 = (tid & 3) * 16;
  float mp[4], lp[4];
  float m = -1e30f;
  #pragma unroll
  for (int p = 0; p < 4; p++) {
    mp[p] = mlpart[(bh * 4 + p) * 128 + row * 2];
    lp[p] = mlpart[(bh * 4 + p) * 128 + row * 2 + 1];
    m = fmaxf(m, mp[p]);
  }
  float a[4]; float L = 0.f;
  #pragma unroll
  for (int p = 0; p < 4; p++) { a[p] = __expf(mp[p] - m); L += lp[p] * a[p]; }
  float rl = 1.f / L;
  u16* op = out + ((size_t)(b * LL + row)) * II + h * DHD + c0;
  #pragma unroll
  for (int j = 0; j < 4; j++) {
    float acc4[4] = {0.f, 0.f, 0.f, 0.f};
    #pragma unroll
    for (int p = 0; p < 4; p++) {
      const float4* pp = (const float4*)(opart + ((size_t)(bh * 4 + p) * 64 + row) * 64 + c0);
      float4 v = pp[j];
      acc4[0] += v.x * a[p]; acc4[1] += v.y * a[p];
      acc4[2] += v.z * a[p]; acc4[3] += v.w * a[p];
    }
    op[j*4 + 0] = f2bf(acc4[0] * rl);
    op[j*4 + 1] = f2bf(acc4[1] * rl);
    op[j*4 + 2] = f2bf(acc4[2] * rl);
    op[j*4 + 3] = f2bf(acc4[3] * rl);
  }
}

extern "C" void kernel_launch(void* const* d_in, const int* in_sizes, int n_in,
                              void* d_out, int out_size, void* d_ws, size_t ws_size,
                              hipStream_t stream) {
  (void)in_sizes; (void)n_in; (void)out_size; (void)ws_size;
  const float* x       = (const float*)d_in[0];
  const int*   mask    = (const int*)d_in[1];
  const float* latents = (const float*)d_in[2];
  const float* ln_m_w  = (const float*)d_in[3];
  const float* ln_m_b  = (const float*)d_in[4];
  const float* ln_l_w  = (const float*)d_in[5];
  const float* ln_l_b  = (const float*)d_in[6];
  const float* Wq      = (const float*)d_in[7];
  const float* Wkv     = (const float*)d_in[8];
  const float* Wo      = (const float*)d_in[9];
  const float* ff_ln_w = (const float*)d_in[10];
  const float* ff_ln_b = (const float*)d_in[11];
  const float* W1      = (const float*)d_in[12];
  const float* W2      = (const float*)d_in[13];
  const float* norm_w  = (const float*)d_in[14];
  const float* norm_b  = (const float*)d_in[15];
  float* out = (float*)d_out;

  char* ws = (char*)d_ws;
  size_t off = 0;
  auto alloc = [&](size_t bytes) -> void* {
    void* p = ws + off; off += (bytes + 255) & ~(size_t)255; return p;
  };
  u16* xcomp = (u16*)alloc((size_t)32768 * 1024 * 2);
  u16* kvk   = (u16*)alloc((size_t)32768 * 512 * 2);
  u16* vT    = (u16*)alloc((size_t)8192 * 2048 * 2);
  int* idxb  = (int*)alloc((size_t)32768 * 4);
  int* cnt   = (int*)alloc(64);
  float* lat = (float*)alloc((size_t)1024 * 1024 * 4);
  u16* lnl   = (u16*)alloc((size_t)1024 * 1024 * 2);
  u16* latn  = (u16*)alloc((size_t)1024 * 1024 * 2);
  u16* qkv   = (u16*)alloc((size_t)1024 * 1536 * 2);
  u16* aout  = (u16*)alloc((size_t)1024 * 512 * 2);
  u16* hf    = (u16*)alloc((size_t)1024 * 4096 * 2);
  float* opart  = (float*)alloc((size_t)512 * 64 * 64 * 4);
  float* mlpart = (float*)alloc((size_t)512 * 128 * 4);
  u16* WqkvT = (u16*)alloc((size_t)DEPTHC * 1536 * 1024 * 2);
  u16* WkvTf = (u16*)alloc((size_t)DEPTHC * 1024 * 1024 * 2);
  u16* WoT   = (u16*)alloc((size_t)DEPTHC * 1024 * 512 * 2);
  u16* W1T   = (u16*)alloc((size_t)DEPTHC * 4096 * 1024 * 2);
  u16* W2T   = (u16*)alloc((size_t)DEPTHC * 1024 * 4096 * 2);
  float* biaskv_all = (float*)alloc(DEPTHC * 1024 * 4);

  // pre-loop: compaction + bias zero, then W1/W2 transposes, then fused qkvo+LN-gather+lat-init
  maskscan_k<<<16, 256, 0, stream>>>(mask, idxb, cnt);
  zero_k<<<24, 256, 0, stream>>>(biaskv_all, DEPTHC * 1024);
  transp_w_k<<<DEPTHC * 1024, 256, 0, stream>>>(W1, W1T, 1024, 4096, 6);
  transp_w_k<<<DEPTHC * 1024, 256, 0, stream>>>(W2, W2T, 4096, 1024, 4);
  qkvo_fused_k<<<3072 + 32768 + 1024, 256, 0, stream>>>(
      Wq, Wkv, Wo, ln_m_w, ln_m_b,
      WqkvT, WoT, WkvTf, biaskv_all,
      x, idxb, cnt, xcomp, latents, lat);

  for (int i = 0; i < DEPTHC; i++) {
    ln_rows_k<false><<<1024, 256, 0, stream>>>(lat, ln_l_w + i*1024, ln_l_b + i*1024, lnl);
    gemm_fused_k<<<2144, 256, 0, stream>>>(
        xcomp, WkvTf + (size_t)i*1024*1024, kvk, vT, biaskv_all + i*1024, cnt,
        lnl, WqkvT + (size_t)i*1536*1024, qkv);
    attn_part_k<<<512, 256, 0, stream>>>(qkv, kvk, vT, cnt, opart, mlpart);
    attn_comb_k<<<128, 256, 0, stream>>>(opart, mlpart, aout);
    gemmsk_k<<<dim3(16, 8, 4), 256, 0, stream>>>(aout, WoT + (size_t)i*1024*512, lat, 1024, 1024, 512, 128);
    ln_rows_k<false><<<1024, 256, 0, stream>>>(lat, ff_ln_w + i*1024, ff_ln_b + i*1024, latn);
    gemm_gelu_k<<<dim3(64, 8), 256, 0, stream>>>(latn, W1T + (size_t)i*4096*1024, hf, 1024, 4096, 1024);
    gemmsk_k<<<dim3(16, 8, 4), 256, 0, stream>>>(hf, W2T + (size_t)i*1024*4096, lat, 1024, 1024, 4096, 1024);
  }
  ln_rows_k<true><<<1024, 256, 0, stream>>>(lat, norm_w, norm_b, out);
}